// Round 2
// baseline (1063.857 us; speedup 1.0000x reference)
//
#include <hip/hip_runtime.h>
#include <math.h>

#define DIM 2048
#define NROWS 4096            // B*S
#define WN (DIM*DIM)
#define HEADS 16
#define HDIM 128
#define SEQ 2048

typedef __attribute__((ext_vector_type(8))) short short8;
typedef __attribute__((ext_vector_type(4))) float floatx4;

__device__ __forceinline__ float bf2f(unsigned short u) {
  return __uint_as_float(((unsigned)u) << 16);
}
__device__ __forceinline__ unsigned short f2bf(float f) {
  unsigned x = __float_as_uint(f);
  x += 0x7FFFu + ((x >> 16) & 1u);   // RTNE
  return (unsigned short)(x >> 16);
}

__device__ __forceinline__ float blockReduceSum(float v, float* red) {
  int tid = threadIdx.x;
  red[tid] = v; __syncthreads();
  for (int s = 128; s > 0; s >>= 1) {
    if (tid < s) red[tid] += red[tid + s];
    __syncthreads();
  }
  float r = red[0]; __syncthreads();
  return r;
}

__device__ __forceinline__ const float* pick_w(const float* a, const float* b,
                                               const float* c, const float* d, int i) {
  return i == 0 ? a : i == 1 ? b : i == 2 ? c : d;
}

// ---------------- weight stats (identical to round 1 — keep reductions bit-stable) ----------------
__global__ __launch_bounds__(256) void w_abs_partial(
    const float* w0, const float* w1, const float* w2, const float* w3, float* part)
{
  const float4* w4 = (const float4*)pick_w(w0, w1, w2, w3, blockIdx.y);
  float s = 0.f;
  for (int i = blockIdx.x * 256 + threadIdx.x; i < WN / 4; i += 1024 * 256) {
    float4 v = w4[i];
    s += fabsf(v.x) + fabsf(v.y) + fabsf(v.z) + fabsf(v.w);
  }
  __shared__ float red[256];
  float t = blockReduceSum(s, red);
  if (threadIdx.x == 0) part[blockIdx.y * 1024 + blockIdx.x] = t;
}

__global__ __launch_bounds__(256) void w_delta_final(const float* part, float* stats)
{
  float s = 0.f;
  for (int i = threadIdx.x; i < 1024; i += 256) s += part[blockIdx.x * 1024 + i];
  __shared__ float red[256];
  float t = blockReduceSum(s, red);
  if (threadIdx.x == 0) stats[blockIdx.x] = 0.7f * (t / (float)WN);
}

__global__ __launch_bounds__(256) void w_mask_partial(
    const float* w0, const float* w1, const float* w2, const float* w3,
    const float* stats, float* part2)
{
  const float4* w4 = (const float4*)pick_w(w0, w1, w2, w3, blockIdx.y);
  float delta = stats[blockIdx.y];
  float s = 0.f, cnt = 0.f;
  for (int i = blockIdx.x * 256 + threadIdx.x; i < WN / 4; i += 1024 * 256) {
    float4 v = w4[i];
    float a;
    a = fabsf(v.x); if (a > delta) { s += a; cnt += 1.f; }
    a = fabsf(v.y); if (a > delta) { s += a; cnt += 1.f; }
    a = fabsf(v.z); if (a > delta) { s += a; cnt += 1.f; }
    a = fabsf(v.w); if (a > delta) { s += a; cnt += 1.f; }
  }
  __shared__ float red[256];
  float ts = blockReduceSum(s, red);
  float tc = blockReduceSum(cnt, red);
  if (threadIdx.x == 0) {
    part2[((size_t)blockIdx.y * 1024 + blockIdx.x) * 2]     = ts;
    part2[((size_t)blockIdx.y * 1024 + blockIdx.x) * 2 + 1] = tc;
  }
}

__global__ __launch_bounds__(256) void w_alpha_final(const float* part2, float* stats)
{
  float s = 0.f, c = 0.f;
  for (int i = threadIdx.x; i < 1024; i += 256) {
    s += part2[((size_t)blockIdx.x * 1024 + i) * 2];
    c += part2[((size_t)blockIdx.x * 1024 + i) * 2 + 1];
  }
  __shared__ float red[256];
  float ts = blockReduceSum(s, red);
  float tc = blockReduceSum(c, red);
  if (threadIdx.x == 0) stats[4 + blockIdx.x] = ts / fmaxf(tc, 1.f);
}

__device__ __forceinline__ unsigned short tq(float a, float delta) {
  if (fabsf(a) > delta) return (a > 0.f) ? (unsigned short)0x3F80u : (unsigned short)0xBF80u;
  return (unsigned short)0;
}

__global__ __launch_bounds__(256) void w_quant(
    const float* w0, const float* w1, const float* w2, const float* w3,
    const float* stats, unsigned short* tern)
{
  int wi = blockIdx.y;
  const float4* w4 = (const float4*)pick_w(w0, w1, w2, w3, wi);
  float delta = stats[wi];
  ushort4* out = (ushort4*)(tern + (size_t)wi * WN);
  for (int i = blockIdx.x * 256 + threadIdx.x; i < WN / 4; i += 1024 * 256) {
    float4 v = w4[i];
    ushort4 o;
    o.x = tq(v.x, delta); o.y = tq(v.y, delta);
    o.z = tq(v.z, delta); o.w = tq(v.w, delta);
    out[i] = o;
  }
}

// ---------------- layernorm (+absmax / +quant) ----------------
template<int MODE>
__global__ __launch_bounds__(256) void ln_kernel(
    const float* __restrict__ x, const float* __restrict__ g, const float* __restrict__ bias,
    unsigned* __restrict__ ambits, unsigned short* __restrict__ xq)
{
  const int row = blockIdx.x, tid = threadIdx.x;
  const float* xr = x + (size_t)row * DIM;
  float4 a0 = *(const float4*)(xr + tid * 4);
  float4 a1 = *(const float4*)(xr + 1024 + tid * 4);
  float s  = a0.x + a0.y + a0.z + a0.w + a1.x + a1.y + a1.z + a1.w;
  float sq = a0.x*a0.x + a0.y*a0.y + a0.z*a0.z + a0.w*a0.w
           + a1.x*a1.x + a1.y*a1.y + a1.z*a1.z + a1.w*a1.w;
  __shared__ float red[256];
  float ts = blockReduceSum(s, red);
  float tqq = blockReduceSum(sq, red);
  float mu = ts * (1.f / DIM);
  float var = tqq * (1.f / DIM) - mu * mu;
  float rstd = 1.f / sqrtf(var + 1e-5f);
  float4 g0 = *(const float4*)(g + tid * 4);
  float4 g1 = *(const float4*)(g + 1024 + tid * 4);
  float4 b0 = *(const float4*)(bias + tid * 4);
  float4 b1 = *(const float4*)(bias + 1024 + tid * 4);
  float y[8];
  y[0] = (a0.x - mu) * rstd * g0.x + b0.x;
  y[1] = (a0.y - mu) * rstd * g0.y + b0.y;
  y[2] = (a0.z - mu) * rstd * g0.z + b0.z;
  y[3] = (a0.w - mu) * rstd * g0.w + b0.w;
  y[4] = (a1.x - mu) * rstd * g1.x + b1.x;
  y[5] = (a1.y - mu) * rstd * g1.y + b1.y;
  y[6] = (a1.z - mu) * rstd * g1.z + b1.z;
  y[7] = (a1.w - mu) * rstd * g1.w + b1.w;
  if (MODE == 0) {
    float m = 0.f;
    #pragma unroll
    for (int j = 0; j < 8; ++j) m = fmaxf(m, fabsf(y[j]));
    red[tid] = m; __syncthreads();
    for (int st = 128; st > 0; st >>= 1) {
      if (tid < st) red[tid] = fmaxf(red[tid], red[tid + st]);
      __syncthreads();
    }
    if (tid == 0) atomicMax(ambits, __float_as_uint(red[0]));
  } else {
    float sc = 127.f / fmaxf(__uint_as_float(*ambits), 1e-5f);
    unsigned short o[8];
    #pragma unroll
    for (int j = 0; j < 8; ++j) {
      float qv = rintf(y[j] * sc);
      qv = fminf(fmaxf(qv, -128.f), 127.f);
      o[j] = f2bf(qv);
    }
    ushort4 q0; q0.x = o[0]; q0.y = o[1]; q0.z = o[2]; q0.w = o[3];
    ushort4 q1; q1.x = o[4]; q1.y = o[5]; q1.z = o[6]; q1.w = o[7];
    *(ushort4*)(xq + (size_t)row * DIM + tid * 4) = q0;
    *(ushort4*)(xq + (size_t)row * DIM + 1024 + tid * 4) = q1;
  }
}

// ---------------- quantized GEMM ----------------
// OMODE: 0 = fp32 out, 1 = bf16 out, 2 = bf16 hi + bf16 lo out
template<int OMODE>
__global__ __launch_bounds__(256) void gemm_bt(
    const unsigned short* __restrict__ A, const unsigned short* __restrict__ Bt,
    void* __restrict__ Cp0, void* __restrict__ Cp1,
    const float* __restrict__ stats, int wi)
{
  const int tid = threadIdx.x;
  const int lane = tid & 63;
  const int w = tid >> 6;
  const int wm = w >> 1, wn = w & 1;
  const int quad = lane >> 4, l16 = lane & 15;
  const int bm = blockIdx.x * 128, bn = blockIdx.y * 128;

  __shared__ __align__(16) unsigned short As[128][72];
  __shared__ __align__(16) unsigned short Bs[128][72];

  floatx4 acc[4][4];
  #pragma unroll
  for (int i = 0; i < 4; ++i)
    #pragma unroll
    for (int j = 0; j < 4; ++j) acc[i][j] = {0.f, 0.f, 0.f, 0.f};

  for (int k0 = 0; k0 < DIM; k0 += 64) {
    #pragma unroll
    for (int c = 0; c < 4; ++c) {
      int idx = c * 256 + tid;
      int row = idx >> 3, cb = (idx & 7) << 3;
      *(uint4*)&As[row][cb] = *(const uint4*)(A + (size_t)(bm + row) * DIM + k0 + cb);
      *(uint4*)&Bs[row][cb] = *(const uint4*)(Bt + (size_t)(bn + row) * DIM + k0 + cb);
    }
    __syncthreads();
    #pragma unroll
    for (int kc = 0; kc < 2; ++kc) {
      short8 af[4], bf[4];
      #pragma unroll
      for (int i = 0; i < 4; ++i)
        af[i] = *(const short8*)&As[wm * 64 + i * 16 + l16][kc * 32 + quad * 8];
      #pragma unroll
      for (int j = 0; j < 4; ++j)
        bf[j] = *(const short8*)&Bs[wn * 64 + j * 16 + l16][kc * 32 + quad * 8];
      #pragma unroll
      for (int i = 0; i < 4; ++i)
        #pragma unroll
        for (int j = 0; j < 4; ++j)
          acc[i][j] = __builtin_amdgcn_mfma_f32_16x16x32_bf16(af[i], bf[j], acc[i][j], 0, 0, 0);
    }
    __syncthreads();
  }

  const unsigned* am = (const unsigned*)(stats + 8);
  float scale = stats[4 + wi] * fmaxf(__uint_as_float(am[wi]), 1e-5f) * (1.f / 127.f);
  #pragma unroll
  for (int i = 0; i < 4; ++i)
    #pragma unroll
    for (int j = 0; j < 4; ++j)
      #pragma unroll
      for (int r = 0; r < 4; ++r) {
        int m = bm + wm * 64 + i * 16 + quad * 4 + r;
        int n = bn + wn * 64 + j * 16 + l16;
        size_t idx = (size_t)m * DIM + n;
        float v = acc[i][j][r] * scale;
        if (OMODE == 0) {
          ((float*)Cp0)[idx] = v;
        } else if (OMODE == 1) {
          ((unsigned short*)Cp0)[idx] = f2bf(v);
        } else {
          unsigned short hi = f2bf(v);
          float lo = v - bf2f(hi);          // exact (Sterbenz)
          ((unsigned short*)Cp0)[idx] = hi;
          ((unsigned short*)Cp1)[idx] = f2bf(lo);
        }
      }
}

// ---------------- rope on hi/lo pairs (angle = head_index * inv, per reference) ----------------
__global__ __launch_bounds__(256) void rope_kernel(
    unsigned short* qhi, unsigned short* qlo, unsigned short* khi, unsigned short* klo)
{
  int idx = blockIdx.x * 256 + threadIdx.x;
  int p = idx & 63;
  int h = (idx >> 6) & (HEADS - 1);
  int r = idx >> 10;
  float inv = powf(10000.f, -(float)p * (1.f / 64.f));
  float ang = (float)h * inv;
  float cs = cosf(ang), sn = sinf(ang);
  size_t base = (size_t)r * DIM + h * HDIM + 2 * p;

  {
    float a = bf2f(qhi[base]) + bf2f(qlo[base]);
    float b = bf2f(qhi[base + 1]) + bf2f(qlo[base + 1]);
    float ra = a * cs - b * sn;
    float rb = a * sn + b * cs;
    unsigned short rah = f2bf(ra), rbh = f2bf(rb);
    qhi[base] = rah;     qlo[base] = f2bf(ra - bf2f(rah));
    qhi[base + 1] = rbh; qlo[base + 1] = f2bf(rb - bf2f(rbh));
  }
  {
    float a = bf2f(khi[base]) + bf2f(klo[base]);
    float b = bf2f(khi[base + 1]) + bf2f(klo[base + 1]);
    float ra = a * cs - b * sn;
    float rb = a * sn + b * cs;
    unsigned short rah = f2bf(ra), rbh = f2bf(rb);
    khi[base] = rah;     klo[base] = f2bf(ra - bf2f(rah));
    khi[base + 1] = rbh; klo[base + 1] = f2bf(rb - bf2f(rbh));
  }
}

// ---------------- transpose V: [b*S+s][h*128+d] -> [(b*16+h)*128+d][s] ----------------
__global__ __launch_bounds__(256) void transpose_v(
    const unsigned short* __restrict__ vin, unsigned short* __restrict__ vout)
{
  __shared__ __align__(16) unsigned short t[64][72];
  const int tid = threadIdx.x;
  const int c0 = blockIdx.x * 64, r0 = blockIdx.y * 64;
  #pragma unroll
  for (int c = 0; c < 2; ++c) {
    int idx = c * 256 + tid;
    int row = idx >> 3, cb = (idx & 7) << 3;
    *(uint4*)&t[row][cb] = *(const uint4*)(vin + (size_t)(r0 + row) * DIM + c0 + cb);
  }
  __syncthreads();
  const int b = r0 >> 11, s0 = r0 & (SEQ - 1);
  const int h = c0 >> 7, d0 = c0 & (HDIM - 1);
  #pragma unroll
  for (int c = 0; c < 2; ++c) {
    int idx = c * 256 + tid;
    int drow = idx >> 3, sb = (idx & 7) << 3;
    union { unsigned short u[8]; uint4 v; } pk;
    #pragma unroll
    for (int j = 0; j < 8; ++j) pk.u[j] = t[sb + j][drow];
    *(uint4*)(vout + (size_t)((b * HEADS + h) * HDIM + d0 + drow) * SEQ + s0 + sb) = pk.v;
  }
}

// ---------------- flash attention, hi/lo QK^T + split-P PV, in-register softmax ----------------
__global__ __launch_bounds__(256) void flash_attn(
    const unsigned short* __restrict__ qhi, const unsigned short* __restrict__ qlo,
    const unsigned short* __restrict__ khi, const unsigned short* __restrict__ klo,
    const unsigned short* __restrict__ vt, float* __restrict__ o)
{
  const int tid = threadIdx.x;
  const int lane = tid & 63;
  const int w = tid >> 6;
  const int quad = lane >> 4;
  const int l16 = lane & 15;
  const int qt = blockIdx.x;
  const int bh = blockIdx.y;
  const int b = bh >> 4;
  const int h = bh & 15;

  __shared__ __align__(16) unsigned short Khs[64][136];
  __shared__ __align__(16) unsigned short Kls[64][136];
  __shared__ __align__(16) unsigned short Vs[128][72];      // V^T tile: [d][t]
  __shared__ __align__(16) unsigned short Phs[4][16][72];   // per-wave P hi
  __shared__ __align__(16) unsigned short Pls[4][16][72];   // per-wave P lo

  // Q fragments in registers (A-layout), loaded once
  const size_t qrow = ((size_t)(b * SEQ + qt * 64 + w * 16 + l16)) * DIM + h * HDIM;
  short8 qh[4], ql[4];
  #pragma unroll
  for (int kc = 0; kc < 4; ++kc) {
    qh[kc] = *(const short8*)(qhi + qrow + kc * 32 + quad * 8);
    ql[kc] = *(const short8*)(qlo + qrow + kc * 32 + quad * 8);
  }

  float m_run[4], l_run[4];
  #pragma unroll
  for (int r = 0; r < 4; ++r) { m_run[r] = -INFINITY; l_run[r] = 0.f; }
  floatx4 accO[8];
  #pragma unroll
  for (int i = 0; i < 8; ++i) accO[i] = {0.f, 0.f, 0.f, 0.f};

  const float scale = 0.088388347648318447f;  // 1/sqrt(128)

  for (int kt = 0; kt < SEQ / 64; ++kt) {
    __syncthreads();
    const size_t kbase = ((size_t)(b * SEQ + kt * 64)) * DIM + h * HDIM;
    const size_t vbase = ((size_t)(bh * HDIM)) * SEQ + kt * 64;
    #pragma unroll
    for (int c = 0; c < 4; ++c) {
      int idx = c * 256 + tid;
      int row = idx >> 4, cb = (idx & 15) << 3;
      *(uint4*)&Khs[row][cb] = *(const uint4*)(khi + kbase + (size_t)row * DIM + cb);
      *(uint4*)&Kls[row][cb] = *(const uint4*)(klo + kbase + (size_t)row * DIM + cb);
      int row2 = idx >> 3, cb2 = (idx & 7) << 3;
      *(uint4*)&Vs[row2][cb2] = *(const uint4*)(vt + vbase + (size_t)row2 * SEQ + cb2);
    }
    __syncthreads();

    // S = scale * (Qhi+Qlo)(Khi+Klo)^T  (3-product hi/lo)
    float sreg[4][4];   // [jt][r]
    #pragma unroll
    for (int jt = 0; jt < 4; ++jt) {
      floatx4 acc = {0.f, 0.f, 0.f, 0.f};
      #pragma unroll
      for (int kc = 0; kc < 4; ++kc) {
        short8 bh_ = *(const short8*)&Khs[jt * 16 + l16][kc * 32 + quad * 8];
        short8 bl_ = *(const short8*)&Kls[jt * 16 + l16][kc * 32 + quad * 8];
        acc = __builtin_amdgcn_mfma_f32_16x16x32_bf16(qh[kc], bh_, acc, 0, 0, 0);
        acc = __builtin_amdgcn_mfma_f32_16x16x32_bf16(qh[kc], bl_, acc, 0, 0, 0);
        acc = __builtin_amdgcn_mfma_f32_16x16x32_bf16(ql[kc], bh_, acc, 0, 0, 0);
      }
      #pragma unroll
      for (int r = 0; r < 4; ++r) sreg[jt][r] = acc[r] * scale;
    }

    // in-register online softmax; lane holds rows quad*4+r, cols jt*16+l16
    float alpha[4];
    #pragma unroll
    for (int r = 0; r < 4; ++r) {
      float mx = fmaxf(fmaxf(sreg[0][r], sreg[1][r]), fmaxf(sreg[2][r], sreg[3][r]));
      #pragma unroll
      for (int d = 1; d < 16; d <<= 1) mx = fmaxf(mx, __shfl_xor(mx, d));
      mx = fmaxf(mx, m_run[r]);
      alpha[r] = __expf(m_run[r] - mx);
      m_run[r] = mx;
      float s = 0.f;
      #pragma unroll
      for (int jt = 0; jt < 4; ++jt) {
        float p = __expf(sreg[jt][r] - mx);
        unsigned short phi = f2bf(p);
        float plo = p - bf2f(phi);
        Phs[w][quad * 4 + r][jt * 16 + l16] = phi;
        Pls[w][quad * 4 + r][jt * 16 + l16] = f2bf(plo);
        s += p;
      }
      #pragma unroll
      for (int d = 1; d < 16; d <<= 1) s += __shfl_xor(s, d);
      l_run[r] = l_run[r] * alpha[r] + s;
    }

    // O = O*alpha + (Phi + Plo) @ V
    #pragma unroll
    for (int dt = 0; dt < 8; ++dt) {
      floatx4 acc = accO[dt];
      #pragma unroll
      for (int r = 0; r < 4; ++r) acc[r] *= alpha[r];
      #pragma unroll
      for (int kc = 0; kc < 2; ++kc) {
        short8 pf = *(const short8*)&Phs[w][l16][kc * 32 + quad * 8];
        short8 pl = *(const short8*)&Pls[w][l16][kc * 32 + quad * 8];
        short8 vf = *(const short8*)&Vs[dt * 16 + l16][kc * 32 + quad * 8];
        acc = __builtin_amdgcn_mfma_f32_16x16x32_bf16(pf, vf, acc, 0, 0, 0);
        acc = __builtin_amdgcn_mfma_f32_16x16x32_bf16(pl, vf, acc, 0, 0, 0);
      }
      accO[dt] = acc;
    }
  }

  #pragma unroll
  for (int dt = 0; dt < 8; ++dt) {
    #pragma unroll
    for (int r = 0; r < 4; ++r) {
      int rl = w * 16 + quad * 4 + r;
      float val = accO[dt][r] / l_run[r];
      int grow = b * SEQ + qt * 64 + rl;
      int gcol = h * HDIM + dt * 16 + l16;
      o[(size_t)grow * DIM + gcol] = val;
    }
  }
}

// ---------------- host ----------------
extern "C" void kernel_launch(void* const* d_in, const int* in_sizes, int n_in,
                              void* d_out, int out_size, void* d_ws, size_t ws_size,
                              hipStream_t stream)
{
  (void)in_sizes; (void)n_in; (void)out_size; (void)ws_size;
  const float* x = (const float*)d_in[0];
  const float* w[4]; const float* g[4]; const float* bb[4];
  for (int i = 0; i < 4; ++i) {
    w[i]  = (const float*)d_in[1 + 3 * i];
    g[i]  = (const float*)d_in[2 + 3 * i];
    bb[i] = (const float*)d_in[3 + 3 * i];
  }

  char* base = (char*)d_ws;
  size_t off = 0;
  auto alloc = [&](size_t bytes) {
    char* p = base + off;
    off += (bytes + 255) & ~(size_t)255;
    return p;
  };
  const size_t ACT = (size_t)NROWS * DIM * 2;   // one bf16 activation buffer
  float* stats          = (float*)alloc(64);
  float* part1          = (float*)alloc(4 * 1024 * sizeof(float));
  float* part2          = (float*)alloc(4 * 1024 * 2 * sizeof(float));
  unsigned short* tern  = (unsigned short*)alloc((size_t)4 * WN * 2);
  unsigned short* xq    = (unsigned short*)alloc(ACT);
  unsigned short* qhi   = (unsigned short*)alloc(ACT);
  unsigned short* qlo   = (unsigned short*)alloc(ACT);
  unsigned short* khi   = (unsigned short*)alloc(ACT);
  unsigned short* klo   = (unsigned short*)alloc(ACT);
  unsigned short* vtb   = (unsigned short*)alloc(ACT);
  unsigned short* vb    = (unsigned short*)alloc(ACT);
  alloc(ACT);                                   // tail so oat (fp32) can overlay vb+tail
  float* oat = (float*)vb;                      // vb dead after transpose_v
  unsigned* ambits = (unsigned*)(stats + 8);

  hipMemsetAsync(stats, 0, 64, stream);

  dim3 b256(256);
  w_abs_partial<<<dim3(1024, 4), b256, 0, stream>>>(w[0], w[1], w[2], w[3], part1);
  w_delta_final<<<4, b256, 0, stream>>>(part1, stats);
  w_mask_partial<<<dim3(1024, 4), b256, 0, stream>>>(w[0], w[1], w[2], w[3], stats, part2);
  w_alpha_final<<<4, b256, 0, stream>>>(part2, stats);
  w_quant<<<dim3(1024, 4), b256, 0, stream>>>(w[0], w[1], w[2], w[3], stats, tern);

  dim3 ggrid(NROWS / 128, DIM / 128);
  // Q projection -> hi/lo
  ln_kernel<0><<<NROWS, b256, 0, stream>>>(x, g[0], bb[0], ambits + 0, nullptr);
  ln_kernel<1><<<NROWS, b256, 0, stream>>>(x, g[0], bb[0], ambits + 0, xq);
  gemm_bt<2><<<ggrid, b256, 0, stream>>>(xq, tern + (size_t)0 * WN, qhi, qlo, stats, 0);
  // K projection -> hi/lo
  ln_kernel<0><<<NROWS, b256, 0, stream>>>(x, g[1], bb[1], ambits + 1, nullptr);
  ln_kernel<1><<<NROWS, b256, 0, stream>>>(x, g[1], bb[1], ambits + 1, xq);
  gemm_bt<2><<<ggrid, b256, 0, stream>>>(xq, tern + (size_t)1 * WN, khi, klo, stats, 1);
  // V projection -> bf16
  ln_kernel<0><<<NROWS, b256, 0, stream>>>(x, g[2], bb[2], ambits + 2, nullptr);
  ln_kernel<1><<<NROWS, b256, 0, stream>>>(x, g[2], bb[2], ambits + 2, xq);
  gemm_bt<1><<<ggrid, b256, 0, stream>>>(xq, tern + (size_t)2 * WN, vb, nullptr, stats, 2);

  rope_kernel<<<NROWS * 1024 / 256, b256, 0, stream>>>(qhi, qlo, khi, klo);
  transpose_v<<<dim3(DIM / 64, NROWS / 64), b256, 0, stream>>>(vb, vtb);
  flash_attn<<<dim3(SEQ / 64, 32), b256, 0, stream>>>(qhi, qlo, khi, klo, vtb, oat);

  ln_kernel<0><<<NROWS, b256, 0, stream>>>(oat, g[3], bb[3], ambits + 3, nullptr);
  ln_kernel<1><<<NROWS, b256, 0, stream>>>(oat, g[3], bb[3], ambits + 3, xq);
  gemm_bt<0><<<ggrid, b256, 0, stream>>>(xq, tern + (size_t)3 * WN, d_out, nullptr, stats, 3);
}

// Round 4
// 903.992 us; speedup vs baseline: 1.1768x; 1.1768x over previous
//
#include <hip/hip_runtime.h>
#include <math.h>

#define DIM 2048
#define NROWS 4096            // B*S
#define WN (DIM*DIM)
#define HEADS 16
#define HDIM 128
#define SEQ 2048

typedef __attribute__((ext_vector_type(8))) short short8;
typedef __attribute__((ext_vector_type(8))) _Float16 half8;
typedef __attribute__((ext_vector_type(4))) float floatx4;

__device__ __forceinline__ float bf2f(unsigned short u) {
  return __uint_as_float(((unsigned)u) << 16);
}
__device__ __forceinline__ unsigned short f2bf(float f) {
  unsigned x = __float_as_uint(f);
  x += 0x7FFFu + ((x >> 16) & 1u);   // RTNE
  return (unsigned short)(x >> 16);
}
__device__ __forceinline__ unsigned short f2h(float f) {
  _Float16 h = (_Float16)f;
  return __builtin_bit_cast(unsigned short, h);
}
__device__ __forceinline__ float h2f(unsigned short u) {
  _Float16 h = __builtin_bit_cast(_Float16, u);
  return (float)h;
}

__device__ __forceinline__ float blockReduceSum(float v, float* red) {
  int tid = threadIdx.x;
  red[tid] = v; __syncthreads();
  for (int s = 128; s > 0; s >>= 1) {
    if (tid < s) red[tid] += red[tid + s];
    __syncthreads();
  }
  float r = red[0]; __syncthreads();
  return r;
}
__device__ __forceinline__ float blockReduceMax(float v, float* red) {
  int tid = threadIdx.x;
  red[tid] = v; __syncthreads();
  for (int s = 128; s > 0; s >>= 1) {
    if (tid < s) red[tid] = fmaxf(red[tid], red[tid + s]);
    __syncthreads();
  }
  float r = red[0]; __syncthreads();
  return r;
}

__device__ __forceinline__ const float* pick_w(const float* a, const float* b,
                                               const float* c, const float* d, int i) {
  return i == 0 ? a : i == 1 ? b : i == 2 ? c : d;
}

// ---------------- weight stats ----------------
__global__ __launch_bounds__(256) void w_abs_partial(
    const float* w0, const float* w1, const float* w2, const float* w3, float* part)
{
  const float4* w4 = (const float4*)pick_w(w0, w1, w2, w3, blockIdx.y);
  float s = 0.f;
  for (int i = blockIdx.x * 256 + threadIdx.x; i < WN / 4; i += 1024 * 256) {
    float4 v = w4[i];
    s += fabsf(v.x) + fabsf(v.y) + fabsf(v.z) + fabsf(v.w);
  }
  __shared__ float red[256];
  float t = blockReduceSum(s, red);
  if (threadIdx.x == 0) part[blockIdx.y * 1024 + blockIdx.x] = t;
}

__global__ __launch_bounds__(256) void w_delta_final(const float* part, float* stats)
{
  float s = 0.f;
  for (int i = threadIdx.x; i < 1024; i += 256) s += part[blockIdx.x * 1024 + i];
  __shared__ float red[256];
  float t = blockReduceSum(s, red);
  if (threadIdx.x == 0) stats[blockIdx.x] = 0.7f * (t / (float)WN);
}

__global__ __launch_bounds__(256) void w_mask_partial(
    const float* w0, const float* w1, const float* w2, const float* w3,
    const float* stats, float* part2)
{
  const float4* w4 = (const float4*)pick_w(w0, w1, w2, w3, blockIdx.y);
  float delta = stats[blockIdx.y];
  float s = 0.f, cnt = 0.f;
  for (int i = blockIdx.x * 256 + threadIdx.x; i < WN / 4; i += 1024 * 256) {
    float4 v = w4[i];
    float a;
    a = fabsf(v.x); if (a > delta) { s += a; cnt += 1.f; }
    a = fabsf(v.y); if (a > delta) { s += a; cnt += 1.f; }
    a = fabsf(v.z); if (a > delta) { s += a; cnt += 1.f; }
    a = fabsf(v.w); if (a > delta) { s += a; cnt += 1.f; }
  }
  __shared__ float red[256];
  float ts = blockReduceSum(s, red);
  float tc = blockReduceSum(cnt, red);
  if (threadIdx.x == 0) {
    part2[((size_t)blockIdx.y * 1024 + blockIdx.x) * 2]     = ts;
    part2[((size_t)blockIdx.y * 1024 + blockIdx.x) * 2 + 1] = tc;
  }
}

__global__ __launch_bounds__(256) void w_alpha_final(const float* part2, float* stats)
{
  float s = 0.f, c = 0.f;
  for (int i = threadIdx.x; i < 1024; i += 256) {
    s += part2[((size_t)blockIdx.x * 1024 + i) * 2];
    c += part2[((size_t)blockIdx.x * 1024 + i) * 2 + 1];
  }
  __shared__ float red[256];
  float ts = blockReduceSum(s, red);
  float tc = blockReduceSum(c, red);
  if (threadIdx.x == 0) stats[4 + blockIdx.x] = ts / fmaxf(tc, 1.f);
}

__device__ __forceinline__ unsigned short tq(float a, float delta) {
  if (fabsf(a) > delta) return (a > 0.f) ? (unsigned short)0x3F80u : (unsigned short)0xBF80u;
  return (unsigned short)0;
}

__global__ __launch_bounds__(256) void w_quant(
    const float* w0, const float* w1, const float* w2, const float* w3,
    const float* stats, unsigned short* tern)
{
  int wi = blockIdx.y;
  const float4* w4 = (const float4*)pick_w(w0, w1, w2, w3, wi);
  float delta = stats[wi];
  ushort4* out = (ushort4*)(tern + (size_t)wi * WN);
  for (int i = blockIdx.x * 256 + threadIdx.x; i < WN / 4; i += 1024 * 256) {
    float4 v = w4[i];
    ushort4 o;
    o.x = tq(v.x, delta); o.y = tq(v.y, delta);
    o.z = tq(v.z, delta); o.w = tq(v.w, delta);
    out[i] = o;
  }
}

// ---------------- fused LN for q/k/v ----------------
__global__ __launch_bounds__(256) void ln_absmax3(
    const float* __restrict__ x,
    const float* __restrict__ g0, const float* __restrict__ b0,
    const float* __restrict__ g1, const float* __restrict__ b1,
    const float* __restrict__ g2, const float* __restrict__ b2,
    unsigned* __restrict__ ambits)
{
  const int row = blockIdx.x, tid = threadIdx.x;
  const float* xr = x + (size_t)row * DIM;
  float4 a0 = *(const float4*)(xr + tid * 4);
  float4 a1 = *(const float4*)(xr + 1024 + tid * 4);
  float s  = a0.x + a0.y + a0.z + a0.w + a1.x + a1.y + a1.z + a1.w;
  float sq = a0.x*a0.x + a0.y*a0.y + a0.z*a0.z + a0.w*a0.w
           + a1.x*a1.x + a1.y*a1.y + a1.z*a1.z + a1.w*a1.w;
  __shared__ float red[256];
  float ts = blockReduceSum(s, red);
  float tqq = blockReduceSum(sq, red);
  float mu = ts * (1.f / DIM);
  float var = tqq * (1.f / DIM) - mu * mu;
  float rstd = 1.f / sqrtf(var + 1e-5f);
  float yn[8];
  yn[0] = (a0.x - mu) * rstd; yn[1] = (a0.y - mu) * rstd;
  yn[2] = (a0.z - mu) * rstd; yn[3] = (a0.w - mu) * rstd;
  yn[4] = (a1.x - mu) * rstd; yn[5] = (a1.y - mu) * rstd;
  yn[6] = (a1.z - mu) * rstd; yn[7] = (a1.w - mu) * rstd;
  const float* gs[3] = {g0, g1, g2};
  const float* bs[3] = {b0, b1, b2};
  #pragma unroll
  for (int p = 0; p < 3; ++p) {
    float4 gg0 = *(const float4*)(gs[p] + tid * 4);
    float4 gg1 = *(const float4*)(gs[p] + 1024 + tid * 4);
    float4 bb0 = *(const float4*)(bs[p] + tid * 4);
    float4 bb1 = *(const float4*)(bs[p] + 1024 + tid * 4);
    float m = fabsf(yn[0] * gg0.x + bb0.x);
    m = fmaxf(m, fabsf(yn[1] * gg0.y + bb0.y));
    m = fmaxf(m, fabsf(yn[2] * gg0.z + bb0.z));
    m = fmaxf(m, fabsf(yn[3] * gg0.w + bb0.w));
    m = fmaxf(m, fabsf(yn[4] * gg1.x + bb1.x));
    m = fmaxf(m, fabsf(yn[5] * gg1.y + bb1.y));
    m = fmaxf(m, fabsf(yn[6] * gg1.z + bb1.z));
    m = fmaxf(m, fabsf(yn[7] * gg1.w + bb1.w));
    float bm = blockReduceMax(m, red);
    if (tid == 0) atomicMax(ambits + p, __float_as_uint(bm));
  }
}

__global__ __launch_bounds__(256) void ln_quant3(
    const float* __restrict__ x,
    const float* __restrict__ g0, const float* __restrict__ b0,
    const float* __restrict__ g1, const float* __restrict__ b1,
    const float* __restrict__ g2, const float* __restrict__ b2,
    const unsigned* __restrict__ ambits,
    unsigned short* __restrict__ xq0, unsigned short* __restrict__ xq1,
    unsigned short* __restrict__ xq2)
{
  const int row = blockIdx.x, tid = threadIdx.x;
  const float* xr = x + (size_t)row * DIM;
  float4 a0 = *(const float4*)(xr + tid * 4);
  float4 a1 = *(const float4*)(xr + 1024 + tid * 4);
  float s  = a0.x + a0.y + a0.z + a0.w + a1.x + a1.y + a1.z + a1.w;
  float sq = a0.x*a0.x + a0.y*a0.y + a0.z*a0.z + a0.w*a0.w
           + a1.x*a1.x + a1.y*a1.y + a1.z*a1.z + a1.w*a1.w;
  __shared__ float red[256];
  float ts = blockReduceSum(s, red);
  float tqq = blockReduceSum(sq, red);
  float mu = ts * (1.f / DIM);
  float var = tqq * (1.f / DIM) - mu * mu;
  float rstd = 1.f / sqrtf(var + 1e-5f);
  float yn[8];
  yn[0] = (a0.x - mu) * rstd; yn[1] = (a0.y - mu) * rstd;
  yn[2] = (a0.z - mu) * rstd; yn[3] = (a0.w - mu) * rstd;
  yn[4] = (a1.x - mu) * rstd; yn[5] = (a1.y - mu) * rstd;
  yn[6] = (a1.z - mu) * rstd; yn[7] = (a1.w - mu) * rstd;
  const float* gs[3] = {g0, g1, g2};
  const float* bs[3] = {b0, b1, b2};
  unsigned short* outs[3] = {xq0, xq1, xq2};
  #pragma unroll
  for (int p = 0; p < 3; ++p) {
    float4 gg0 = *(const float4*)(gs[p] + tid * 4);
    float4 gg1 = *(const float4*)(gs[p] + 1024 + tid * 4);
    float4 bb0 = *(const float4*)(bs[p] + tid * 4);
    float4 bb1 = *(const float4*)(bs[p] + 1024 + tid * 4);
    float y[8];
    y[0] = yn[0] * gg0.x + bb0.x; y[1] = yn[1] * gg0.y + bb0.y;
    y[2] = yn[2] * gg0.z + bb0.z; y[3] = yn[3] * gg0.w + bb0.w;
    y[4] = yn[4] * gg1.x + bb1.x; y[5] = yn[5] * gg1.y + bb1.y;
    y[6] = yn[6] * gg1.z + bb1.z; y[7] = yn[7] * gg1.w + bb1.w;
    float sc = 127.f / fmaxf(__uint_as_float(ambits[p]), 1e-5f);
    unsigned short o[8];
    #pragma unroll
    for (int j = 0; j < 8; ++j) {
      float qv = rintf(y[j] * sc);
      qv = fminf(fmaxf(qv, -128.f), 127.f);
      o[j] = f2bf(qv);                        // exact: |int| <= 128
    }
    ushort4 q0; q0.x = o[0]; q0.y = o[1]; q0.z = o[2]; q0.w = o[3];
    ushort4 q1; q1.x = o[4]; q1.y = o[5]; q1.z = o[6]; q1.w = o[7];
    *(ushort4*)(outs[p] + (size_t)row * DIM + tid * 4) = q0;
    *(ushort4*)(outs[p] + (size_t)row * DIM + 1024 + tid * 4) = q1;
  }
}

// ---------------- single-tensor LN (for the o projection) ----------------
template<int MODE>
__global__ __launch_bounds__(256) void ln_kernel(
    const float* __restrict__ x, const float* __restrict__ g, const float* __restrict__ bias,
    unsigned* __restrict__ ambits, unsigned short* __restrict__ xq)
{
  const int row = blockIdx.x, tid = threadIdx.x;
  const float* xr = x + (size_t)row * DIM;
  float4 a0 = *(const float4*)(xr + tid * 4);
  float4 a1 = *(const float4*)(xr + 1024 + tid * 4);
  float s  = a0.x + a0.y + a0.z + a0.w + a1.x + a1.y + a1.z + a1.w;
  float sq = a0.x*a0.x + a0.y*a0.y + a0.z*a0.z + a0.w*a0.w
           + a1.x*a1.x + a1.y*a1.y + a1.z*a1.z + a1.w*a1.w;
  __shared__ float red[256];
  float ts = blockReduceSum(s, red);
  float tqq = blockReduceSum(sq, red);
  float mu = ts * (1.f / DIM);
  float var = tqq * (1.f / DIM) - mu * mu;
  float rstd = 1.f / sqrtf(var + 1e-5f);
  float4 g0 = *(const float4*)(g + tid * 4);
  float4 g1 = *(const float4*)(g + 1024 + tid * 4);
  float4 b0 = *(const float4*)(bias + tid * 4);
  float4 b1 = *(const float4*)(bias + 1024 + tid * 4);
  float y[8];
  y[0] = (a0.x - mu) * rstd * g0.x + b0.x;
  y[1] = (a0.y - mu) * rstd * g0.y + b0.y;
  y[2] = (a0.z - mu) * rstd * g0.z + b0.z;
  y[3] = (a0.w - mu) * rstd * g0.w + b0.w;
  y[4] = (a1.x - mu) * rstd * g1.x + b1.x;
  y[5] = (a1.y - mu) * rstd * g1.y + b1.y;
  y[6] = (a1.z - mu) * rstd * g1.z + b1.z;
  y[7] = (a1.w - mu) * rstd * g1.w + b1.w;
  if (MODE == 0) {
    float m = 0.f;
    #pragma unroll
    for (int j = 0; j < 8; ++j) m = fmaxf(m, fabsf(y[j]));
    float bm = blockReduceMax(m, red);
    if (tid == 0) atomicMax(ambits, __float_as_uint(bm));
  } else {
    float sc = 127.f / fmaxf(__uint_as_float(*ambits), 1e-5f);
    unsigned short o[8];
    #pragma unroll
    for (int j = 0; j < 8; ++j) {
      float qv = rintf(y[j] * sc);
      qv = fminf(fmaxf(qv, -128.f), 127.f);
      o[j] = f2bf(qv);
    }
    ushort4 q0; q0.x = o[0]; q0.y = o[1]; q0.z = o[2]; q0.w = o[3];
    ushort4 q1; q1.x = o[4]; q1.y = o[5]; q1.z = o[6]; q1.w = o[7];
    *(ushort4*)(xq + (size_t)row * DIM + tid * 4) = q0;
    *(ushort4*)(xq + (size_t)row * DIM + 1024 + tid * 4) = q1;
  }
}

// ---------------- quantized GEMM: C[m,n] = scale * sum_k A[m,k]*Bt[n,k] ----------------
// OMODE: 0 = fp32 out, 1 = fp16 out
template<int OMODE>
__global__ __launch_bounds__(256) void gemm_bt(
    const unsigned short* __restrict__ A, const unsigned short* __restrict__ Bt,
    void* __restrict__ Cp0, const float* __restrict__ stats, int wi)
{
  const int tid = threadIdx.x;
  const int lane = tid & 63;
  const int w = tid >> 6;
  const int wm = w >> 1, wn = w & 1;
  const int quad = lane >> 4, l16 = lane & 15;
  const int bm = blockIdx.x * 128, bn = blockIdx.y * 128;

  __shared__ __align__(16) unsigned short As[128][72];
  __shared__ __align__(16) unsigned short Bs[128][72];

  floatx4 acc[4][4];
  #pragma unroll
  for (int i = 0; i < 4; ++i)
    #pragma unroll
    for (int j = 0; j < 4; ++j) acc[i][j] = {0.f, 0.f, 0.f, 0.f};

  for (int k0 = 0; k0 < DIM; k0 += 64) {
    #pragma unroll
    for (int c = 0; c < 4; ++c) {
      int idx = c * 256 + tid;
      int row = idx >> 3, cb = (idx & 7) << 3;
      *(uint4*)&As[row][cb] = *(const uint4*)(A + (size_t)(bm + row) * DIM + k0 + cb);
      *(uint4*)&Bs[row][cb] = *(const uint4*)(Bt + (size_t)(bn + row) * DIM + k0 + cb);
    }
    __syncthreads();
    #pragma unroll
    for (int kc = 0; kc < 2; ++kc) {
      short8 af[4], bf[4];
      #pragma unroll
      for (int i = 0; i < 4; ++i)
        af[i] = *(const short8*)&As[wm * 64 + i * 16 + l16][kc * 32 + quad * 8];
      #pragma unroll
      for (int j = 0; j < 4; ++j)
        bf[j] = *(const short8*)&Bs[wn * 64 + j * 16 + l16][kc * 32 + quad * 8];
      #pragma unroll
      for (int i = 0; i < 4; ++i)
        #pragma unroll
        for (int j = 0; j < 4; ++j)
          acc[i][j] = __builtin_amdgcn_mfma_f32_16x16x32_bf16(af[i], bf[j], acc[i][j], 0, 0, 0);
    }
    __syncthreads();
  }

  const unsigned* am = (const unsigned*)(stats + 8);
  float scale = stats[4 + wi] * fmaxf(__uint_as_float(am[wi]), 1e-5f) * (1.f / 127.f);
  #pragma unroll
  for (int i = 0; i < 4; ++i)
    #pragma unroll
    for (int j = 0; j < 4; ++j)
      #pragma unroll
      for (int r = 0; r < 4; ++r) {
        int m = bm + wm * 64 + i * 16 + quad * 4 + r;
        int n = bn + wn * 64 + j * 16 + l16;
        size_t idx = (size_t)m * DIM + n;
        float v = acc[i][j][r] * scale;
        if (OMODE == 0) ((float*)Cp0)[idx] = v;
        else            ((unsigned short*)Cp0)[idx] = f2h(v);
      }
}

// ---------------- rope (fp16; angle = head_index * inv, per reference) ----------------
__global__ __launch_bounds__(256) void rope_kernel(unsigned short* q, unsigned short* k)
{
  int idx = blockIdx.x * 256 + threadIdx.x;
  int p = idx & 63;
  int h = (idx >> 6) & (HEADS - 1);
  int r = idx >> 10;
  float inv = powf(10000.f, -(float)p * (1.f / 64.f));
  float ang = (float)h * inv;
  float cs = cosf(ang), sn = sinf(ang);
  size_t base = (size_t)r * DIM + h * HDIM + 2 * p;
  {
    float a = h2f(q[base]), b = h2f(q[base + 1]);
    q[base]     = f2h(a * cs - b * sn);
    q[base + 1] = f2h(a * sn + b * cs);
  }
  {
    float a = h2f(k[base]), b = h2f(k[base + 1]);
    k[base]     = f2h(a * cs - b * sn);
    k[base + 1] = f2h(a * sn + b * cs);
  }
}

// ---------------- transpose V: [b*S+s][h*128+d] -> [(b*16+h)*128+d][s] ----------------
__global__ __launch_bounds__(256) void transpose_v(
    const unsigned short* __restrict__ vin, unsigned short* __restrict__ vout)
{
  __shared__ __align__(16) unsigned short t[64][72];
  const int tid = threadIdx.x;
  const int c0 = blockIdx.x * 64, r0 = blockIdx.y * 64;
  #pragma unroll
  for (int c = 0; c < 2; ++c) {
    int idx = c * 256 + tid;
    int row = idx >> 3, cb = (idx & 7) << 3;
    *(uint4*)&t[row][cb] = *(const uint4*)(vin + (size_t)(r0 + row) * DIM + c0 + cb);
  }
  __syncthreads();
  const int b = r0 >> 11, s0 = r0 & (SEQ - 1);
  const int h = c0 >> 7, d0 = c0 & (HDIM - 1);
  #pragma unroll
  for (int c = 0; c < 2; ++c) {
    int idx = c * 256 + tid;
    int drow = idx >> 3, sb = (idx & 7) << 3;
    union { unsigned short u[8]; uint4 v; } pk;
    #pragma unroll
    for (int j = 0; j < 8; ++j) pk.u[j] = t[sb + j][drow];
    *(uint4*)(vout + (size_t)((b * HEADS + h) * HDIM + d0 + drow) * SEQ + s0 + sb) = pk.v;
  }
}

// ---------------- flash attention: R2-proven 16x16 structure, fp16 single ----------------
__global__ __launch_bounds__(256) void flash_attn(
    const unsigned short* __restrict__ qf, const unsigned short* __restrict__ kf,
    const unsigned short* __restrict__ vt, float* __restrict__ o)
{
  const int tid = threadIdx.x;
  const int lane = tid & 63;
  const int w = tid >> 6;
  const int quad = lane >> 4;
  const int l16 = lane & 15;
  const int qt = blockIdx.x;
  const int bh = blockIdx.y;
  const int b = bh >> 4;
  const int h = bh & 15;

  __shared__ __align__(16) unsigned short Ks[64][136];
  __shared__ __align__(16) unsigned short Vs[128][72];      // V^T tile: [d][t]
  __shared__ __align__(16) unsigned short Ps[4][16][72];    // per-wave P (q x t)

  // Q fragments in registers (A-layout), loaded once
  const size_t qrow = ((size_t)(b * SEQ + qt * 64 + w * 16 + l16)) * DIM + h * HDIM;
  short8 qa[4];
  #pragma unroll
  for (int kc = 0; kc < 4; ++kc)
    qa[kc] = *(const short8*)(qf + qrow + kc * 32 + quad * 8);

  float m_run[4], l_run[4];
  #pragma unroll
  for (int r = 0; r < 4; ++r) { m_run[r] = -INFINITY; l_run[r] = 0.f; }
  floatx4 accO[8];
  #pragma unroll
  for (int i = 0; i < 8; ++i) accO[i] = {0.f, 0.f, 0.f, 0.f};

  const float scale = 0.088388347648318447f;  // 1/sqrt(128)

  for (int kt = 0; kt < SEQ / 64; ++kt) {
    __syncthreads();
    const size_t kbase = ((size_t)(b * SEQ + kt * 64)) * DIM + h * HDIM;
    const size_t vbase = ((size_t)bh * HDIM) * SEQ + kt * 64;
    #pragma unroll
    for (int c = 0; c < 4; ++c) {
      int idx = c * 256 + tid;
      int row = idx >> 4, cb = (idx & 15) << 3;
      *(uint4*)&Ks[row][cb] = *(const uint4*)(kf + kbase + (size_t)row * DIM + cb);
      int row2 = idx >> 3, cb2 = (idx & 7) << 3;
      *(uint4*)&Vs[row2][cb2] = *(const uint4*)(vt + vbase + (size_t)row2 * SEQ + cb2);
    }
    __syncthreads();

    // S = scale * Q K^T
    float sreg[4][4];   // [jt][r]
    #pragma unroll
    for (int jt = 0; jt < 4; ++jt) {
      floatx4 acc = {0.f, 0.f, 0.f, 0.f};
      #pragma unroll
      for (int kc = 0; kc < 4; ++kc) {
        short8 kb = *(const short8*)&Ks[jt * 16 + l16][kc * 32 + quad * 8];
        acc = __builtin_amdgcn_mfma_f32_16x16x32_f16(
            __builtin_bit_cast(half8, qa[kc]), __builtin_bit_cast(half8, kb), acc, 0, 0, 0);
      }
      #pragma unroll
      for (int r = 0; r < 4; ++r) sreg[jt][r] = acc[r] * scale;
    }

    // in-register online softmax; lane holds rows quad*4+r, cols jt*16+l16
    float alpha[4];
    #pragma unroll
    for (int r = 0; r < 4; ++r) {
      float mx = fmaxf(fmaxf(sreg[0][r], sreg[1][r]), fmaxf(sreg[2][r], sreg[3][r]));
      #pragma unroll
      for (int d = 1; d < 16; d <<= 1) mx = fmaxf(mx, __shfl_xor(mx, d));
      mx = fmaxf(mx, m_run[r]);
      alpha[r] = __expf(m_run[r] - mx);   // expf(-inf)=0 on first tile
      m_run[r] = mx;
      float s = 0.f;
      #pragma unroll
      for (int jt = 0; jt < 4; ++jt) {
        float p = __expf(sreg[jt][r] - mx);
        unsigned short ph = f2h(p);
        Ps[w][quad * 4 + r][jt * 16 + l16] = ph;
        s += h2f(ph);                     // l consistent with fp16 P used in PV
      }
      #pragma unroll
      for (int d = 1; d < 16; d <<= 1) s += __shfl_xor(s, d);
      l_run[r] = l_run[r] * alpha[r] + s;
    }

    // O = O*alpha + P @ V
    #pragma unroll
    for (int dt = 0; dt < 8; ++dt) {
      floatx4 acc = accO[dt];
      #pragma unroll
      for (int r = 0; r < 4; ++r) acc[r] *= alpha[r];
      #pragma unroll
      for (int kc = 0; kc < 2; ++kc) {
        short8 pf = *(const short8*)&Ps[w][l16][kc * 32 + quad * 8];
        short8 vf = *(const short8*)&Vs[dt * 16 + l16][kc * 32 + quad * 8];
        acc = __builtin_amdgcn_mfma_f32_16x16x32_f16(
            __builtin_bit_cast(half8, pf), __builtin_bit_cast(half8, vf), acc, 0, 0, 0);
      }
      accO[dt] = acc;
    }
  }

  #pragma unroll
  for (int dt = 0; dt < 8; ++dt) {
    #pragma unroll
    for (int r = 0; r < 4; ++r) {
      int rl = w * 16 + quad * 4 + r;
      float val = accO[dt][r] / l_run[r];
      int grow = b * SEQ + qt * 64 + rl;
      int gcol = h * HDIM + dt * 16 + l16;
      o[(size_t)grow * DIM + gcol] = val;
    }
  }
}

// ---------------- host ----------------
extern "C" void kernel_launch(void* const* d_in, const int* in_sizes, int n_in,
                              void* d_out, int out_size, void* d_ws, size_t ws_size,
                              hipStream_t stream)
{
  (void)in_sizes; (void)n_in; (void)out_size; (void)ws_size;
  const float* x = (const float*)d_in[0];
  const float* w[4]; const float* g[4]; const float* bb[4];
  for (int i = 0; i < 4; ++i) {
    w[i]  = (const float*)d_in[1 + 3 * i];
    g[i]  = (const float*)d_in[2 + 3 * i];
    bb[i] = (const float*)d_in[3 + 3 * i];
  }

  char* base = (char*)d_ws;
  size_t off = 0;
  auto alloc = [&](size_t bytes) {
    char* p = base + off;
    off += (bytes + 255) & ~(size_t)255;
    return p;
  };
  const size_t ACT = (size_t)NROWS * DIM * 2;   // one 16-bit activation buffer (16 MB)
  float* stats          = (float*)alloc(64);
  float* part1          = (float*)alloc(4 * 1024 * sizeof(float));
  float* part2          = (float*)alloc(4 * 1024 * 2 * sizeof(float));
  unsigned short* tern  = (unsigned short*)alloc((size_t)4 * WN * 2);
  unsigned short* xq0   = (unsigned short*)alloc(ACT);
  unsigned short* xq1   = (unsigned short*)alloc(ACT);
  unsigned short* xq2   = (unsigned short*)alloc(ACT);
  unsigned short* qh    = (unsigned short*)alloc(ACT);
  unsigned short* kh    = (unsigned short*)alloc(ACT);
  unsigned short* vb    = (unsigned short*)alloc(ACT);
  unsigned short* vtb   = (unsigned short*)alloc(ACT);
  float* oat = (float*)xq0;            // 32 MB overlay: xq0+xq1 dead after the q/k GEMMs
  unsigned short* xqo = xq2;           // dead after the v GEMM
  unsigned* ambits = (unsigned*)(stats + 8);

  hipMemsetAsync(stats, 0, 64, stream);

  dim3 b256(256);
  w_abs_partial<<<dim3(1024, 4), b256, 0, stream>>>(w[0], w[1], w[2], w[3], part1);
  w_delta_final<<<4, b256, 0, stream>>>(part1, stats);
  w_mask_partial<<<dim3(1024, 4), b256, 0, stream>>>(w[0], w[1], w[2], w[3], stats, part2);
  w_alpha_final<<<4, b256, 0, stream>>>(part2, stats);
  w_quant<<<dim3(1024, 4), b256, 0, stream>>>(w[0], w[1], w[2], w[3], stats, tern);

  ln_absmax3<<<NROWS, b256, 0, stream>>>(x, g[0], bb[0], g[1], bb[1], g[2], bb[2], ambits);
  ln_quant3<<<NROWS, b256, 0, stream>>>(x, g[0], bb[0], g[1], bb[1], g[2], bb[2], ambits,
                                        xq0, xq1, xq2);

  dim3 ggrid(NROWS / 128, DIM / 128);
  gemm_bt<1><<<ggrid, b256, 0, stream>>>(xq0, tern + (size_t)0 * WN, qh, stats, 0);
  gemm_bt<1><<<ggrid, b256, 0, stream>>>(xq1, tern + (size_t)1 * WN, kh, stats, 1);
  gemm_bt<1><<<ggrid, b256, 0, stream>>>(xq2, tern + (size_t)2 * WN, vb, stats, 2);

  rope_kernel<<<NROWS * 1024 / 256, b256, 0, stream>>>(qh, kh);
  transpose_v<<<dim3(DIM / 64, NROWS / 64), b256, 0, stream>>>(vb, vtb);
  flash_attn<<<dim3(SEQ / 64, 32), b256, 0, stream>>>(qh, kh, vtb, oat);

  ln_kernel<0><<<NROWS, b256, 0, stream>>>(oat, g[3], bb[3], ambits + 3, nullptr);
  ln_kernel<1><<<NROWS, b256, 0, stream>>>(oat, g[3], bb[3], ambits + 3, xqo);
  gemm_bt<0><<<ggrid, b256, 0, stream>>>(xqo, tern + (size_t)3 * WN, (float*)d_out, stats, 3);
}

// Round 5
// 874.403 us; speedup vs baseline: 1.2167x; 1.0338x over previous
//
#include <hip/hip_runtime.h>
#include <math.h>

#define DIM 2048
#define NROWS 4096            // B*S
#define WN (DIM*DIM)
#define HEADS 16
#define HDIM 128
#define SEQ 2048

typedef __attribute__((ext_vector_type(8))) short short8;
typedef __attribute__((ext_vector_type(8))) _Float16 half8;
typedef __attribute__((ext_vector_type(4))) float floatx4;

__device__ __forceinline__ float bf2f(unsigned short u) {
  return __uint_as_float(((unsigned)u) << 16);
}
__device__ __forceinline__ unsigned short f2bf(float f) {
  unsigned x = __float_as_uint(f);
  x += 0x7FFFu + ((x >> 16) & 1u);   // RTNE
  return (unsigned short)(x >> 16);
}
__device__ __forceinline__ unsigned short f2h(float f) {
  _Float16 h = (_Float16)f;
  return __builtin_bit_cast(unsigned short, h);
}
__device__ __forceinline__ float h2f(unsigned short u) {
  _Float16 h = __builtin_bit_cast(_Float16, u);
  return (float)h;
}

// async global->LDS, 16B per lane; lds base must be wave-uniform (HW scatters lane i at +i*16)
__device__ __forceinline__ void gload_lds16(const unsigned short* g, unsigned short* l) {
  __builtin_amdgcn_global_load_lds(
      (const __attribute__((address_space(1))) unsigned int*)(const void*)g,
      (__attribute__((address_space(3))) unsigned int*)(void*)l, 16, 0, 0);
}

__device__ __forceinline__ float blockReduceSum(float v, float* red) {
  int tid = threadIdx.x;
  red[tid] = v; __syncthreads();
  for (int s = 128; s > 0; s >>= 1) {
    if (tid < s) red[tid] += red[tid + s];
    __syncthreads();
  }
  float r = red[0]; __syncthreads();
  return r;
}
__device__ __forceinline__ float blockReduceMax(float v, float* red) {
  int tid = threadIdx.x;
  red[tid] = v; __syncthreads();
  for (int s = 128; s > 0; s >>= 1) {
    if (tid < s) red[tid] = fmaxf(red[tid], red[tid + s]);
    __syncthreads();
  }
  float r = red[0]; __syncthreads();
  return r;
}

__device__ __forceinline__ const float* pick_w(const float* a, const float* b,
                                               const float* c, const float* d, int i) {
  return i == 0 ? a : i == 1 ? b : i == 2 ? c : d;
}

// ---------------- weight stats ----------------
__global__ __launch_bounds__(256) void w_abs_partial(
    const float* w0, const float* w1, const float* w2, const float* w3, float* part)
{
  const float4* w4 = (const float4*)pick_w(w0, w1, w2, w3, blockIdx.y);
  float s = 0.f;
  for (int i = blockIdx.x * 256 + threadIdx.x; i < WN / 4; i += 1024 * 256) {
    float4 v = w4[i];
    s += fabsf(v.x) + fabsf(v.y) + fabsf(v.z) + fabsf(v.w);
  }
  __shared__ float red[256];
  float t = blockReduceSum(s, red);
  if (threadIdx.x == 0) part[blockIdx.y * 1024 + blockIdx.x] = t;
}

__global__ __launch_bounds__(256) void w_delta_final(const float* part, float* stats)
{
  float s = 0.f;
  for (int i = threadIdx.x; i < 1024; i += 256) s += part[blockIdx.x * 1024 + i];
  __shared__ float red[256];
  float t = blockReduceSum(s, red);
  if (threadIdx.x == 0) stats[blockIdx.x] = 0.7f * (t / (float)WN);
}

__global__ __launch_bounds__(256) void w_mask_partial(
    const float* w0, const float* w1, const float* w2, const float* w3,
    const float* stats, float* part2)
{
  const float4* w4 = (const float4*)pick_w(w0, w1, w2, w3, blockIdx.y);
  float delta = stats[blockIdx.y];
  float s = 0.f, cnt = 0.f;
  for (int i = blockIdx.x * 256 + threadIdx.x; i < WN / 4; i += 1024 * 256) {
    float4 v = w4[i];
    float a;
    a = fabsf(v.x); if (a > delta) { s += a; cnt += 1.f; }
    a = fabsf(v.y); if (a > delta) { s += a; cnt += 1.f; }
    a = fabsf(v.z); if (a > delta) { s += a; cnt += 1.f; }
    a = fabsf(v.w); if (a > delta) { s += a; cnt += 1.f; }
  }
  __shared__ float red[256];
  float ts = blockReduceSum(s, red);
  float tc = blockReduceSum(cnt, red);
  if (threadIdx.x == 0) {
    part2[((size_t)blockIdx.y * 1024 + blockIdx.x) * 2]     = ts;
    part2[((size_t)blockIdx.y * 1024 + blockIdx.x) * 2 + 1] = tc;
  }
}

__global__ __launch_bounds__(256) void w_alpha_final(const float* part2, float* stats)
{
  float s = 0.f, c = 0.f;
  for (int i = threadIdx.x; i < 1024; i += 256) {
    s += part2[((size_t)blockIdx.x * 1024 + i) * 2];
    c += part2[((size_t)blockIdx.x * 1024 + i) * 2 + 1];
  }
  __shared__ float red[256];
  float ts = blockReduceSum(s, red);
  float tc = blockReduceSum(c, red);
  if (threadIdx.x == 0) stats[4 + blockIdx.x] = ts / fmaxf(tc, 1.f);
}

__device__ __forceinline__ unsigned short tq(float a, float delta) {
  if (fabsf(a) > delta) return (a > 0.f) ? (unsigned short)0x3F80u : (unsigned short)0xBF80u;
  return (unsigned short)0;
}

__global__ __launch_bounds__(256) void w_quant(
    const float* w0, const float* w1, const float* w2, const float* w3,
    const float* stats, unsigned short* tern)
{
  int wi = blockIdx.y;
  const float4* w4 = (const float4*)pick_w(w0, w1, w2, w3, wi);
  float delta = stats[wi];
  ushort4* out = (ushort4*)(tern + (size_t)wi * WN);
  for (int i = blockIdx.x * 256 + threadIdx.x; i < WN / 4; i += 1024 * 256) {
    float4 v = w4[i];
    ushort4 o;
    o.x = tq(v.x, delta); o.y = tq(v.y, delta);
    o.z = tq(v.z, delta); o.w = tq(v.w, delta);
    out[i] = o;
  }
}

// ---------------- fused LN for q/k/v ----------------
__global__ __launch_bounds__(256) void ln_absmax3(
    const float* __restrict__ x,
    const float* __restrict__ g0, const float* __restrict__ b0,
    const float* __restrict__ g1, const float* __restrict__ b1,
    const float* __restrict__ g2, const float* __restrict__ b2,
    unsigned* __restrict__ ambits)
{
  const int row = blockIdx.x, tid = threadIdx.x;
  const float* xr = x + (size_t)row * DIM;
  float4 a0 = *(const float4*)(xr + tid * 4);
  float4 a1 = *(const float4*)(xr + 1024 + tid * 4);
  float s  = a0.x + a0.y + a0.z + a0.w + a1.x + a1.y + a1.z + a1.w;
  float sq = a0.x*a0.x + a0.y*a0.y + a0.z*a0.z + a0.w*a0.w
           + a1.x*a1.x + a1.y*a1.y + a1.z*a1.z + a1.w*a1.w;
  __shared__ float red[256];
  float ts = blockReduceSum(s, red);
  float tqq = blockReduceSum(sq, red);
  float mu = ts * (1.f / DIM);
  float var = tqq * (1.f / DIM) - mu * mu;
  float rstd = 1.f / sqrtf(var + 1e-5f);
  float yn[8];
  yn[0] = (a0.x - mu) * rstd; yn[1] = (a0.y - mu) * rstd;
  yn[2] = (a0.z - mu) * rstd; yn[3] = (a0.w - mu) * rstd;
  yn[4] = (a1.x - mu) * rstd; yn[5] = (a1.y - mu) * rstd;
  yn[6] = (a1.z - mu) * rstd; yn[7] = (a1.w - mu) * rstd;
  const float* gs[3] = {g0, g1, g2};
  const float* bs[3] = {b0, b1, b2};
  #pragma unroll
  for (int p = 0; p < 3; ++p) {
    float4 gg0 = *(const float4*)(gs[p] + tid * 4);
    float4 gg1 = *(const float4*)(gs[p] + 1024 + tid * 4);
    float4 bb0 = *(const float4*)(bs[p] + tid * 4);
    float4 bb1 = *(const float4*)(bs[p] + 1024 + tid * 4);
    float m = fabsf(yn[0] * gg0.x + bb0.x);
    m = fmaxf(m, fabsf(yn[1] * gg0.y + bb0.y));
    m = fmaxf(m, fabsf(yn[2] * gg0.z + bb0.z));
    m = fmaxf(m, fabsf(yn[3] * gg0.w + bb0.w));
    m = fmaxf(m, fabsf(yn[4] * gg1.x + bb1.x));
    m = fmaxf(m, fabsf(yn[5] * gg1.y + bb1.y));
    m = fmaxf(m, fabsf(yn[6] * gg1.z + bb1.z));
    m = fmaxf(m, fabsf(yn[7] * gg1.w + bb1.w));
    float bm = blockReduceMax(m, red);
    if (tid == 0) atomicMax(ambits + p, __float_as_uint(bm));
  }
}

__global__ __launch_bounds__(256) void ln_quant3(
    const float* __restrict__ x,
    const float* __restrict__ g0, const float* __restrict__ b0,
    const float* __restrict__ g1, const float* __restrict__ b1,
    const float* __restrict__ g2, const float* __restrict__ b2,
    const unsigned* __restrict__ ambits,
    unsigned short* __restrict__ xq0, unsigned short* __restrict__ xq1,
    unsigned short* __restrict__ xq2)
{
  const int row = blockIdx.x, tid = threadIdx.x;
  const float* xr = x + (size_t)row * DIM;
  float4 a0 = *(const float4*)(xr + tid * 4);
  float4 a1 = *(const float4*)(xr + 1024 + tid * 4);
  float s  = a0.x + a0.y + a0.z + a0.w + a1.x + a1.y + a1.z + a1.w;
  float sq = a0.x*a0.x + a0.y*a0.y + a0.z*a0.z + a0.w*a0.w
           + a1.x*a1.x + a1.y*a1.y + a1.z*a1.z + a1.w*a1.w;
  __shared__ float red[256];
  float ts = blockReduceSum(s, red);
  float tqq = blockReduceSum(sq, red);
  float mu = ts * (1.f / DIM);
  float var = tqq * (1.f / DIM) - mu * mu;
  float rstd = 1.f / sqrtf(var + 1e-5f);
  float yn[8];
  yn[0] = (a0.x - mu) * rstd; yn[1] = (a0.y - mu) * rstd;
  yn[2] = (a0.z - mu) * rstd; yn[3] = (a0.w - mu) * rstd;
  yn[4] = (a1.x - mu) * rstd; yn[5] = (a1.y - mu) * rstd;
  yn[6] = (a1.z - mu) * rstd; yn[7] = (a1.w - mu) * rstd;
  const float* gs[3] = {g0, g1, g2};
  const float* bs[3] = {b0, b1, b2};
  unsigned short* outs[3] = {xq0, xq1, xq2};
  #pragma unroll
  for (int p = 0; p < 3; ++p) {
    float4 gg0 = *(const float4*)(gs[p] + tid * 4);
    float4 gg1 = *(const float4*)(gs[p] + 1024 + tid * 4);
    float4 bb0 = *(const float4*)(bs[p] + tid * 4);
    float4 bb1 = *(const float4*)(bs[p] + 1024 + tid * 4);
    float y[8];
    y[0] = yn[0] * gg0.x + bb0.x; y[1] = yn[1] * gg0.y + bb0.y;
    y[2] = yn[2] * gg0.z + bb0.z; y[3] = yn[3] * gg0.w + bb0.w;
    y[4] = yn[4] * gg1.x + bb1.x; y[5] = yn[5] * gg1.y + bb1.y;
    y[6] = yn[6] * gg1.z + bb1.z; y[7] = yn[7] * gg1.w + bb1.w;
    float sc = 127.f / fmaxf(__uint_as_float(ambits[p]), 1e-5f);
    unsigned short o[8];
    #pragma unroll
    for (int j = 0; j < 8; ++j) {
      float qv = rintf(y[j] * sc);
      qv = fminf(fmaxf(qv, -128.f), 127.f);
      o[j] = f2bf(qv);                        // exact: |int| <= 128
    }
    ushort4 q0; q0.x = o[0]; q0.y = o[1]; q0.z = o[2]; q0.w = o[3];
    ushort4 q1; q1.x = o[4]; q1.y = o[5]; q1.z = o[6]; q1.w = o[7];
    *(ushort4*)(outs[p] + (size_t)row * DIM + tid * 4) = q0;
    *(ushort4*)(outs[p] + (size_t)row * DIM + 1024 + tid * 4) = q1;
  }
}

// ---------------- single-tensor LN (for the o projection) ----------------
template<int MODE>
__global__ __launch_bounds__(256) void ln_kernel(
    const float* __restrict__ x, const float* __restrict__ g, const float* __restrict__ bias,
    unsigned* __restrict__ ambits, unsigned short* __restrict__ xq)
{
  const int row = blockIdx.x, tid = threadIdx.x;
  const float* xr = x + (size_t)row * DIM;
  float4 a0 = *(const float4*)(xr + tid * 4);
  float4 a1 = *(const float4*)(xr + 1024 + tid * 4);
  float s  = a0.x + a0.y + a0.z + a0.w + a1.x + a1.y + a1.z + a1.w;
  float sq = a0.x*a0.x + a0.y*a0.y + a0.z*a0.z + a0.w*a0.w
           + a1.x*a1.x + a1.y*a1.y + a1.z*a1.z + a1.w*a1.w;
  __shared__ float red[256];
  float ts = blockReduceSum(s, red);
  float tqq = blockReduceSum(sq, red);
  float mu = ts * (1.f / DIM);
  float var = tqq * (1.f / DIM) - mu * mu;
  float rstd = 1.f / sqrtf(var + 1e-5f);
  float4 g0 = *(const float4*)(g + tid * 4);
  float4 g1 = *(const float4*)(g + 1024 + tid * 4);
  float4 b0 = *(const float4*)(bias + tid * 4);
  float4 b1 = *(const float4*)(bias + 1024 + tid * 4);
  float y[8];
  y[0] = (a0.x - mu) * rstd * g0.x + b0.x;
  y[1] = (a0.y - mu) * rstd * g0.y + b0.y;
  y[2] = (a0.z - mu) * rstd * g0.z + b0.z;
  y[3] = (a0.w - mu) * rstd * g0.w + b0.w;
  y[4] = (a1.x - mu) * rstd * g1.x + b1.x;
  y[5] = (a1.y - mu) * rstd * g1.y + b1.y;
  y[6] = (a1.z - mu) * rstd * g1.z + b1.z;
  y[7] = (a1.w - mu) * rstd * g1.w + b1.w;
  if (MODE == 0) {
    float m = 0.f;
    #pragma unroll
    for (int j = 0; j < 8; ++j) m = fmaxf(m, fabsf(y[j]));
    float bm = blockReduceMax(m, red);
    if (tid == 0) atomicMax(ambits, __float_as_uint(bm));
  } else {
    float sc = 127.f / fmaxf(__uint_as_float(*ambits), 1e-5f);
    unsigned short o[8];
    #pragma unroll
    for (int j = 0; j < 8; ++j) {
      float qv = rintf(y[j] * sc);
      qv = fminf(fmaxf(qv, -128.f), 127.f);
      o[j] = f2bf(qv);
    }
    ushort4 q0; q0.x = o[0]; q0.y = o[1]; q0.z = o[2]; q0.w = o[3];
    ushort4 q1; q1.x = o[4]; q1.y = o[5]; q1.z = o[6]; q1.w = o[7];
    *(ushort4*)(xq + (size_t)row * DIM + tid * 4) = q0;
    *(ushort4*)(xq + (size_t)row * DIM + 1024 + tid * 4) = q1;
  }
}

// ---------------- quantized GEMM, m97 structure: global_load_lds staging ----------------
// OMODE: 0 = fp32 out, 1 = fp16 out
template<int OMODE>
__global__ __launch_bounds__(256) void gemm_bt(
    const unsigned short* __restrict__ A, const unsigned short* __restrict__ Bt,
    void* __restrict__ Cp0, const float* __restrict__ stats, int wi)
{
  const int tid = threadIdx.x;
  const int lane = tid & 63;
  const int w = tid >> 6;
  const int wm = w >> 1, wn = w & 1;
  const int quad = lane >> 4, l16 = lane & 15;
  const int bm = blockIdx.x * 128, bn = blockIdx.y * 128;

  // unpadded, contiguous row-major [128][64] — required by global_load_lds lane scatter
  __shared__ __align__(16) unsigned short As[128 * 64];
  __shared__ __align__(16) unsigned short Bs[128 * 64];

  // per-chunk geometry: chunk c (1 KiB) = rows c*8..c*8+8; lane i -> row c*8+(i>>3), col (i&7)*8
  const int srow_off = lane >> 3;        // 0..7
  const int scol     = (lane & 7) * 8;   // halves

  floatx4 acc[4][4];
  #pragma unroll
  for (int i = 0; i < 4; ++i)
    #pragma unroll
    for (int j = 0; j < 4; ++j) acc[i][j] = {0.f, 0.f, 0.f, 0.f};

  for (int k0 = 0; k0 < DIM; k0 += 64) {
    #pragma unroll
    for (int i = 0; i < 4; ++i) {
      int c = i * 4 + w;                 // wave-uniform chunk id
      int row = c * 8 + srow_off;
      gload_lds16(A  + (size_t)(bm + row) * DIM + k0 + scol, &As[c * 512]);
      gload_lds16(Bt + (size_t)(bn + row) * DIM + k0 + scol, &Bs[c * 512]);
    }
    __syncthreads();                     // drains vmcnt before barrier (compiler-emitted)
    #pragma unroll
    for (int kc = 0; kc < 2; ++kc) {
      short8 af[4], bf[4];
      #pragma unroll
      for (int i = 0; i < 4; ++i)
        af[i] = *(const short8*)&As[(wm * 64 + i * 16 + l16) * 64 + kc * 32 + quad * 8];
      #pragma unroll
      for (int j = 0; j < 4; ++j)
        bf[j] = *(const short8*)&Bs[(wn * 64 + j * 16 + l16) * 64 + kc * 32 + quad * 8];
      #pragma unroll
      for (int i = 0; i < 4; ++i)
        #pragma unroll
        for (int j = 0; j < 4; ++j)
          acc[i][j] = __builtin_amdgcn_mfma_f32_16x16x32_bf16(af[i], bf[j], acc[i][j], 0, 0, 0);
    }
    __syncthreads();
  }

  const unsigned* am = (const unsigned*)(stats + 8);
  float scale = stats[4 + wi] * fmaxf(__uint_as_float(am[wi]), 1e-5f) * (1.f / 127.f);
  #pragma unroll
  for (int i = 0; i < 4; ++i)
    #pragma unroll
    for (int j = 0; j < 4; ++j)
      #pragma unroll
      for (int r = 0; r < 4; ++r) {
        int m = bm + wm * 64 + i * 16 + quad * 4 + r;
        int n = bn + wn * 64 + j * 16 + l16;
        size_t idx = (size_t)m * DIM + n;
        float v = acc[i][j][r] * scale;
        if (OMODE == 0) ((float*)Cp0)[idx] = v;
        else            ((unsigned short*)Cp0)[idx] = f2h(v);
      }
}

// ---------------- rope (fp16; angle = head_index * inv; q gets (1/sqrt(128))*log2e folded) ----------------
__global__ __launch_bounds__(256) void rope_kernel(unsigned short* q, unsigned short* k)
{
  const float SC = 0.12751741769011063f;   // (1/sqrt(128)) * log2(e)
  int idx = blockIdx.x * 256 + threadIdx.x;
  int p = idx & 63;
  int h = (idx >> 6) & (HEADS - 1);
  int r = idx >> 10;
  float inv = exp2f((float)p * -0.20762050593046f);  // 10000^(-p/64)
  float ang = (float)h * inv;
  float sn, cs;
  __sincosf(ang, &sn, &cs);
  size_t base = (size_t)r * DIM + h * HDIM + 2 * p;
  {
    float a = h2f(q[base]), b = h2f(q[base + 1]);
    q[base]     = f2h((a * cs - b * sn) * SC);
    q[base + 1] = f2h((a * sn + b * cs) * SC);
  }
  {
    float a = h2f(k[base]), b = h2f(k[base + 1]);
    k[base]     = f2h(a * cs - b * sn);
    k[base + 1] = f2h(a * sn + b * cs);
  }
}

// ---------------- transpose V: [b*S+s][h*128+d] -> [(b*16+h)*128+d][s] ----------------
__global__ __launch_bounds__(256) void transpose_v(
    const unsigned short* __restrict__ vin, unsigned short* __restrict__ vout)
{
  __shared__ __align__(16) unsigned short t[64][72];
  const int tid = threadIdx.x;
  const int c0 = blockIdx.x * 64, r0 = blockIdx.y * 64;
  #pragma unroll
  for (int c = 0; c < 2; ++c) {
    int idx = c * 256 + tid;
    int row = idx >> 3, cb = (idx & 7) << 3;
    *(uint4*)&t[row][cb] = *(const uint4*)(vin + (size_t)(r0 + row) * DIM + c0 + cb);
  }
  __syncthreads();
  const int b = r0 >> 11, s0 = r0 & (SEQ - 1);
  const int h = c0 >> 7, d0 = c0 & (HDIM - 1);
  #pragma unroll
  for (int c = 0; c < 2; ++c) {
    int idx = c * 256 + tid;
    int drow = idx >> 3, sb = (idx & 7) << 3;
    union { unsigned short u[8]; uint4 v; } pk;
    #pragma unroll
    for (int j = 0; j < 8; ++j) pk.u[j] = t[sb + j][drow];
    *(uint4*)(vout + (size_t)((b * HEADS + h) * HDIM + d0 + drow) * SEQ + s0 + sb) = pk.v;
  }
}

// ---------------- flash attention: S^T formulation (operand-swapped), per-lane softmax ----------------
// Q pre-scaled by (1/sqrt(128))*log2(e); softmax in exp2 domain.
__global__ __launch_bounds__(256) void flash_attn(
    const unsigned short* __restrict__ qf, const unsigned short* __restrict__ kf,
    const unsigned short* __restrict__ vt, float* __restrict__ o)
{
  const int tid = threadIdx.x;
  const int lane = tid & 63;
  const int w = tid >> 6;
  const int quad = lane >> 4;
  const int l16 = lane & 15;
  const int qt = blockIdx.x;
  const int bh = blockIdx.y;
  const int b = bh >> 4;
  const int h = bh & 15;

  __shared__ __align__(16) unsigned short Ks[64][136];
  __shared__ __align__(16) unsigned short Vs[128][72];      // V^T tile: [d][t]
  __shared__ __align__(16) unsigned short Ps[4][16][72];    // per-wave P: [q][t]

  // Q fragment (B-operand): lane n=l16 -> q row; k = kc*32 + quad*8 + j
  const size_t qrow = ((size_t)(b * SEQ + qt * 64 + w * 16 + l16)) * DIM + h * HDIM;
  short8 qa[4];
  #pragma unroll
  for (int kc = 0; kc < 4; ++kc)
    qa[kc] = *(const short8*)(qf + qrow + kc * 32 + quad * 8);

  float m_q = -INFINITY, l_q = 0.f;     // per-lane: q = l16 (replicated across quads)
  floatx4 accO[8];                      // O^T: [dt] rows d=dt*16+quad*4+r, col q=l16
  #pragma unroll
  for (int i = 0; i < 8; ++i) accO[i] = {0.f, 0.f, 0.f, 0.f};

  for (int kt = 0; kt < SEQ / 64; ++kt) {
    __syncthreads();
    const size_t kbase = ((size_t)(b * SEQ + kt * 64)) * DIM + h * HDIM;
    const size_t vbase = ((size_t)bh * HDIM) * SEQ + kt * 64;
    #pragma unroll
    for (int c = 0; c < 4; ++c) {
      int idx = c * 256 + tid;
      int row = idx >> 4, cb = (idx & 15) << 3;
      *(uint4*)&Ks[row][cb] = *(const uint4*)(kf + kbase + (size_t)row * DIM + cb);
      int row2 = idx >> 3, cb2 = (idx & 7) << 3;
      *(uint4*)&Vs[row2][cb2] = *(const uint4*)(vt + vbase + (size_t)row2 * SEQ + cb2);
    }
    __syncthreads();

    // S^T = K Q'^T : lane holds q=l16, keys t = jt*16 + quad*4 + r
    float sreg[4][4];
    #pragma unroll
    for (int jt = 0; jt < 4; ++jt) {
      floatx4 acc = {0.f, 0.f, 0.f, 0.f};
      #pragma unroll
      for (int kc = 0; kc < 4; ++kc) {
        short8 kb = *(const short8*)&Ks[jt * 16 + l16][kc * 32 + quad * 8];
        acc = __builtin_amdgcn_mfma_f32_16x16x32_f16(
            __builtin_bit_cast(half8, kb), __builtin_bit_cast(half8, qa[kc]), acc, 0, 0, 0);
      }
      #pragma unroll
      for (int r = 0; r < 4; ++r) sreg[jt][r] = acc[r];
    }

    // per-lane online softmax (exp2 domain); reduce across quads with 2 shuffles
    float mx = sreg[0][0];
    #pragma unroll
    for (int jt = 0; jt < 4; ++jt)
      #pragma unroll
      for (int r = 0; r < 4; ++r) mx = fmaxf(mx, sreg[jt][r]);
    mx = fmaxf(mx, __shfl_xor(mx, 16));
    mx = fmaxf(mx, __shfl_xor(mx, 32));
    float mnew = fmaxf(m_q, mx);
    float alpha = exp2f(m_q - mnew);    // exp2f(-inf)=0 on first tile
    m_q = mnew;
    float ssum = 0.f;
    #pragma unroll
    for (int jt = 0; jt < 4; ++jt) {
      ushort4 pk;
      float p0 = exp2f(sreg[jt][0] - mnew);
      float p1 = exp2f(sreg[jt][1] - mnew);
      float p2 = exp2f(sreg[jt][2] - mnew);
      float p3 = exp2f(sreg[jt][3] - mnew);
      pk.x = f2h(p0); pk.y = f2h(p1); pk.z = f2h(p2); pk.w = f2h(p3);
      ssum += (p0 + p1) + (p2 + p3);
      *(ushort4*)&Ps[w][l16][jt * 16 + quad * 4] = pk;   // t = jt*16+quad*4 .. +3
    }
    ssum += __shfl_xor(ssum, 16);
    ssum += __shfl_xor(ssum, 32);
    l_q = l_q * alpha + ssum;

    // O^T = O^T*alpha + V^T P^T  (A = V^T fragment, B = P row of lane's q)
    #pragma unroll
    for (int dt = 0; dt < 8; ++dt) {
      #pragma unroll
      for (int r = 0; r < 4; ++r) accO[dt][r] *= alpha;
    }
    #pragma unroll
    for (int kc = 0; kc < 2; ++kc) {
      short8 pf = *(const short8*)&Ps[w][l16][kc * 32 + quad * 8];
      #pragma unroll
      for (int dt = 0; dt < 8; ++dt) {
        short8 vf = *(const short8*)&Vs[dt * 16 + l16][kc * 32 + quad * 8];
        accO[dt] = __builtin_amdgcn_mfma_f32_16x16x32_f16(
            __builtin_bit_cast(half8, vf), __builtin_bit_cast(half8, pf), accO[dt], 0, 0, 0);
      }
    }
  }

  // epilogue: lane q=l16 holds d = dt*16+quad*4+r -> float4 stores, 16B per lane
  float invl = 1.0f / l_q;
  const size_t obase = (size_t)(b * SEQ + qt * 64 + w * 16 + l16) * DIM + h * HDIM;
  #pragma unroll
  for (int dt = 0; dt < 8; ++dt) {
    float4 ov;
    ov.x = accO[dt][0] * invl; ov.y = accO[dt][1] * invl;
    ov.z = accO[dt][2] * invl; ov.w = accO[dt][3] * invl;
    *(float4*)(o + obase + dt * 16 + quad * 4) = ov;
  }
}

// ---------------- host ----------------
extern "C" void kernel_launch(void* const* d_in, const int* in_sizes, int n_in,
                              void* d_out, int out_size, void* d_ws, size_t ws_size,
                              hipStream_t stream)
{
  (void)in_sizes; (void)n_in; (void)out_size; (void)ws_size;
  const float* x = (const float*)d_in[0];
  const float* w[4]; const float* g[4]; const float* bb[4];
  for (int i = 0; i < 4; ++i) {
    w[i]  = (const float*)d_in[1 + 3 * i];
    g[i]  = (const float*)d_in[2 + 3 * i];
    bb[i] = (const float*)d_in[3 + 3 * i];
  }

  char* base = (char*)d_ws;
  size_t off = 0;
  auto alloc = [&](size_t bytes) {
    char* p = base + off;
    off += (bytes + 255) & ~(size_t)255;
    return p;
  };
  const size_t ACT = (size_t)NROWS * DIM * 2;   // one 16-bit activation buffer (16 MB)
  float* stats          = (float*)alloc(64);
  float* part1          = (float*)alloc(4 * 1024 * sizeof(float));
  float* part2          = (float*)alloc(4 * 1024 * 2 * sizeof(float));
  unsigned short* tern  = (unsigned short*)alloc((size_t)4 * WN * 2);
  unsigned short* xq0   = (unsigned short*)alloc(ACT);
  unsigned short* xq1   = (unsigned short*)alloc(ACT);
  unsigned short* xq2   = (unsigned short*)alloc(ACT);
  unsigned short* qh    = (unsigned short*)alloc(ACT);
  unsigned short* kh    = (unsigned short*)alloc(ACT);
  unsigned short* vb    = (unsigned short*)alloc(ACT);
  unsigned short* vtb   = (unsigned short*)alloc(ACT);
  float* oat = (float*)xq0;            // 32 MB overlay: xq0+xq1 dead after the q/k GEMMs
  unsigned short* xqo = xq2;           // dead after the v GEMM
  unsigned* ambits = (unsigned*)(stats + 8);

  hipMemsetAsync(stats, 0, 64, stream);

  dim3 b256(256);
  w_abs_partial<<<dim3(1024, 4), b256, 0, stream>>>(w[0], w[1], w[2], w[3], part1);
  w_delta_final<<<4, b256, 0, stream>>>(part1, stats);
  w_mask_partial<<<dim3(1024, 4), b256, 0, stream>>>(w[0], w[1], w[2], w[3], stats, part2);
  w_alpha_final<<<4, b256, 0, stream>>>(part2, stats);
  w_quant<<<dim3(1024, 4), b256, 0, stream>>>(w[0], w[1], w[2], w[3], stats, tern);

  ln_absmax3<<<NROWS, b256, 0, stream>>>(x, g[0], bb[0], g[1], bb[1], g[2], bb[2], ambits);
  ln_quant3<<<NROWS, b256, 0, stream>>>(x, g[0], bb[0], g[1], bb[1], g[2], bb[2], ambits,
                                        xq0, xq1, xq2);

  dim3 ggrid(NROWS / 128, DIM / 128);
  gemm_bt<1><<<ggrid, b256, 0, stream>>>(xq0, tern + (size_t)0 * WN, qh, stats, 0);
  gemm_bt<1><<<ggrid, b256, 0, stream>>>(xq1, tern + (size_t)1 * WN, kh, stats, 1);
  gemm_bt<1><<<ggrid, b256, 0, stream>>>(xq2, tern + (size_t)2 * WN, vb, stats, 2);

  rope_kernel<<<NROWS * 1024 / 256, b256, 0, stream>>>(qh, kh);
  transpose_v<<<dim3(DIM / 64, NROWS / 64), b256, 0, stream>>>(vb, vtb);
  flash_attn<<<dim3(SEQ / 64, 32), b256, 0, stream>>>(qh, kh, vtb, oat);

  ln_kernel<0><<<NROWS, b256, 0, stream>>>(oat, g[3], bb[3], ambits + 3, nullptr);
  ln_kernel<1><<<NROWS, b256, 0, stream>>>(oat, g[3], bb[3], ambits + 3, xqo);
  gemm_bt<0><<<ggrid, b256, 0, stream>>>(xqo, tern + (size_t)3 * WN, (float*)d_out, stats, 3);
}

// Round 6
// 809.430 us; speedup vs baseline: 1.3143x; 1.0803x over previous
//
#include <hip/hip_runtime.h>
#include <math.h>

#define DIM 2048
#define NROWS 4096            // B*S
#define WN (DIM*DIM)
#define HEADS 16
#define HDIM 128
#define SEQ 2048

typedef __attribute__((ext_vector_type(8))) short short8;
typedef __attribute__((ext_vector_type(8))) _Float16 half8;
typedef __attribute__((ext_vector_type(4))) float floatx4;

__device__ __forceinline__ float bf2f(unsigned short u) {
  return __uint_as_float(((unsigned)u) << 16);
}
__device__ __forceinline__ unsigned short f2bf(float f) {
  unsigned x = __float_as_uint(f);
  x += 0x7FFFu + ((x >> 16) & 1u);   // RTNE
  return (unsigned short)(x >> 16);
}
__device__ __forceinline__ unsigned short f2h(float f) {
  _Float16 h = (_Float16)f;
  return __builtin_bit_cast(unsigned short, h);
}
__device__ __forceinline__ float h2f(unsigned short u) {
  _Float16 h = __builtin_bit_cast(_Float16, u);
  return (float)h;
}

// async global->LDS, 16B per lane; lds base must be wave-uniform (HW scatters lane i at +i*16)
__device__ __forceinline__ void gload_lds16(const unsigned short* g, unsigned short* l) {
  __builtin_amdgcn_global_load_lds(
      (const __attribute__((address_space(1))) unsigned int*)(const void*)g,
      (__attribute__((address_space(3))) unsigned int*)(void*)l, 16, 0, 0);
}

__device__ __forceinline__ float blockReduceSum(float v, float* red) {
  int tid = threadIdx.x;
  red[tid] = v; __syncthreads();
  for (int s = 128; s > 0; s >>= 1) {
    if (tid < s) red[tid] += red[tid + s];
    __syncthreads();
  }
  float r = red[0]; __syncthreads();
  return r;
}
__device__ __forceinline__ float blockReduceMax(float v, float* red) {
  int tid = threadIdx.x;
  red[tid] = v; __syncthreads();
  for (int s = 128; s > 0; s >>= 1) {
    if (tid < s) red[tid] = fmaxf(red[tid], red[tid + s]);
    __syncthreads();
  }
  float r = red[0]; __syncthreads();
  return r;
}

__device__ __forceinline__ const float* pick_w(const float* a, const float* b,
                                               const float* c, const float* d, int i) {
  return i == 0 ? a : i == 1 ? b : i == 2 ? c : d;
}

// ---------------- weight stats ----------------
__global__ __launch_bounds__(256) void w_abs_partial(
    const float* w0, const float* w1, const float* w2, const float* w3, float* part)
{
  const float4* w4 = (const float4*)pick_w(w0, w1, w2, w3, blockIdx.y);
  float s = 0.f;
  for (int i = blockIdx.x * 256 + threadIdx.x; i < WN / 4; i += 1024 * 256) {
    float4 v = w4[i];
    s += fabsf(v.x) + fabsf(v.y) + fabsf(v.z) + fabsf(v.w);
  }
  __shared__ float red[256];
  float t = blockReduceSum(s, red);
  if (threadIdx.x == 0) part[blockIdx.y * 1024 + blockIdx.x] = t;
}

__global__ __launch_bounds__(256) void w_delta_final(const float* part, float* stats)
{
  float s = 0.f;
  for (int i = threadIdx.x; i < 1024; i += 256) s += part[blockIdx.x * 1024 + i];
  __shared__ float red[256];
  float t = blockReduceSum(s, red);
  if (threadIdx.x == 0) stats[blockIdx.x] = 0.7f * (t / (float)WN);
}

__device__ __forceinline__ unsigned short tq(float a, float delta) {
  if (fabsf(a) > delta) return (a > 0.f) ? (unsigned short)0x3F80u : (unsigned short)0xBF80u;
  return (unsigned short)0;
}

// fused: ternary-quantize weights AND accumulate alpha partials (one weight read pass)
__global__ __launch_bounds__(256) void w_maskquant(
    const float* w0, const float* w1, const float* w2, const float* w3,
    const float* stats, float* part2, unsigned short* tern)
{
  int wi = blockIdx.y;
  const float4* w4 = (const float4*)pick_w(w0, w1, w2, w3, wi);
  float delta = stats[wi];
  ushort4* out = (ushort4*)(tern + (size_t)wi * WN);
  float s = 0.f, cnt = 0.f;
  for (int i = blockIdx.x * 256 + threadIdx.x; i < WN / 4; i += 1024 * 256) {
    float4 v = w4[i];
    ushort4 o;
    float a;
    a = fabsf(v.x); if (a > delta) { s += a; cnt += 1.f; } o.x = tq(v.x, delta);
    a = fabsf(v.y); if (a > delta) { s += a; cnt += 1.f; } o.y = tq(v.y, delta);
    a = fabsf(v.z); if (a > delta) { s += a; cnt += 1.f; } o.z = tq(v.z, delta);
    a = fabsf(v.w); if (a > delta) { s += a; cnt += 1.f; } o.w = tq(v.w, delta);
    out[i] = o;
  }
  __shared__ float red[256];
  float ts = blockReduceSum(s, red);
  float tc = blockReduceSum(cnt, red);
  if (threadIdx.x == 0) {
    part2[((size_t)blockIdx.y * 1024 + blockIdx.x) * 2]     = ts;
    part2[((size_t)blockIdx.y * 1024 + blockIdx.x) * 2 + 1] = tc;
  }
}

__global__ __launch_bounds__(256) void w_alpha_final(const float* part2, float* stats)
{
  float s = 0.f, c = 0.f;
  for (int i = threadIdx.x; i < 1024; i += 256) {
    s += part2[((size_t)blockIdx.x * 1024 + i) * 2];
    c += part2[((size_t)blockIdx.x * 1024 + i) * 2 + 1];
  }
  __shared__ float red[256];
  float ts = blockReduceSum(s, red);
  float tc = blockReduceSum(c, red);
  if (threadIdx.x == 0) stats[4 + blockIdx.x] = ts / fmaxf(tc, 1.f);
}

// ---------------- fused LN for q/k/v ----------------
__global__ __launch_bounds__(256) void ln_absmax3(
    const float* __restrict__ x,
    const float* __restrict__ g0, const float* __restrict__ b0,
    const float* __restrict__ g1, const float* __restrict__ b1,
    const float* __restrict__ g2, const float* __restrict__ b2,
    unsigned* __restrict__ ambits)
{
  const int row = blockIdx.x, tid = threadIdx.x;
  const float* xr = x + (size_t)row * DIM;
  float4 a0 = *(const float4*)(xr + tid * 4);
  float4 a1 = *(const float4*)(xr + 1024 + tid * 4);
  float s  = a0.x + a0.y + a0.z + a0.w + a1.x + a1.y + a1.z + a1.w;
  float sq = a0.x*a0.x + a0.y*a0.y + a0.z*a0.z + a0.w*a0.w
           + a1.x*a1.x + a1.y*a1.y + a1.z*a1.z + a1.w*a1.w;
  __shared__ float red[256];
  float ts = blockReduceSum(s, red);
  float tqq = blockReduceSum(sq, red);
  float mu = ts * (1.f / DIM);
  float var = tqq * (1.f / DIM) - mu * mu;
  float rstd = 1.f / sqrtf(var + 1e-5f);
  float yn[8];
  yn[0] = (a0.x - mu) * rstd; yn[1] = (a0.y - mu) * rstd;
  yn[2] = (a0.z - mu) * rstd; yn[3] = (a0.w - mu) * rstd;
  yn[4] = (a1.x - mu) * rstd; yn[5] = (a1.y - mu) * rstd;
  yn[6] = (a1.z - mu) * rstd; yn[7] = (a1.w - mu) * rstd;
  const float* gs[3] = {g0, g1, g2};
  const float* bs[3] = {b0, b1, b2};
  #pragma unroll
  for (int p = 0; p < 3; ++p) {
    float4 gg0 = *(const float4*)(gs[p] + tid * 4);
    float4 gg1 = *(const float4*)(gs[p] + 1024 + tid * 4);
    float4 bb0 = *(const float4*)(bs[p] + tid * 4);
    float4 bb1 = *(const float4*)(bs[p] + 1024 + tid * 4);
    float m = fabsf(yn[0] * gg0.x + bb0.x);
    m = fmaxf(m, fabsf(yn[1] * gg0.y + bb0.y));
    m = fmaxf(m, fabsf(yn[2] * gg0.z + bb0.z));
    m = fmaxf(m, fabsf(yn[3] * gg0.w + bb0.w));
    m = fmaxf(m, fabsf(yn[4] * gg1.x + bb1.x));
    m = fmaxf(m, fabsf(yn[5] * gg1.y + bb1.y));
    m = fmaxf(m, fabsf(yn[6] * gg1.z + bb1.z));
    m = fmaxf(m, fabsf(yn[7] * gg1.w + bb1.w));
    float bm = blockReduceMax(m, red);
    if (tid == 0) atomicMax(ambits + p, __float_as_uint(bm));
  }
}

__global__ __launch_bounds__(256) void ln_quant3(
    const float* __restrict__ x,
    const float* __restrict__ g0, const float* __restrict__ b0,
    const float* __restrict__ g1, const float* __restrict__ b1,
    const float* __restrict__ g2, const float* __restrict__ b2,
    const unsigned* __restrict__ ambits,
    unsigned short* __restrict__ xq0, unsigned short* __restrict__ xq1,
    unsigned short* __restrict__ xq2)
{
  const int row = blockIdx.x, tid = threadIdx.x;
  const float* xr = x + (size_t)row * DIM;
  float4 a0 = *(const float4*)(xr + tid * 4);
  float4 a1 = *(const float4*)(xr + 1024 + tid * 4);
  float s  = a0.x + a0.y + a0.z + a0.w + a1.x + a1.y + a1.z + a1.w;
  float sq = a0.x*a0.x + a0.y*a0.y + a0.z*a0.z + a0.w*a0.w
           + a1.x*a1.x + a1.y*a1.y + a1.z*a1.z + a1.w*a1.w;
  __shared__ float red[256];
  float ts = blockReduceSum(s, red);
  float tqq = blockReduceSum(sq, red);
  float mu = ts * (1.f / DIM);
  float var = tqq * (1.f / DIM) - mu * mu;
  float rstd = 1.f / sqrtf(var + 1e-5f);
  float yn[8];
  yn[0] = (a0.x - mu) * rstd; yn[1] = (a0.y - mu) * rstd;
  yn[2] = (a0.z - mu) * rstd; yn[3] = (a0.w - mu) * rstd;
  yn[4] = (a1.x - mu) * rstd; yn[5] = (a1.y - mu) * rstd;
  yn[6] = (a1.z - mu) * rstd; yn[7] = (a1.w - mu) * rstd;
  const float* gs[3] = {g0, g1, g2};
  const float* bs[3] = {b0, b1, b2};
  unsigned short* outs[3] = {xq0, xq1, xq2};
  #pragma unroll
  for (int p = 0; p < 3; ++p) {
    float4 gg0 = *(const float4*)(gs[p] + tid * 4);
    float4 gg1 = *(const float4*)(gs[p] + 1024 + tid * 4);
    float4 bb0 = *(const float4*)(bs[p] + tid * 4);
    float4 bb1 = *(const float4*)(bs[p] + 1024 + tid * 4);
    float y[8];
    y[0] = yn[0] * gg0.x + bb0.x; y[1] = yn[1] * gg0.y + bb0.y;
    y[2] = yn[2] * gg0.z + bb0.z; y[3] = yn[3] * gg0.w + bb0.w;
    y[4] = yn[4] * gg1.x + bb1.x; y[5] = yn[5] * gg1.y + bb1.y;
    y[6] = yn[6] * gg1.z + bb1.z; y[7] = yn[7] * gg1.w + bb1.w;
    float sc = 127.f / fmaxf(__uint_as_float(ambits[p]), 1e-5f);
    unsigned short o[8];
    #pragma unroll
    for (int j = 0; j < 8; ++j) {
      float qv = rintf(y[j] * sc);
      qv = fminf(fmaxf(qv, -128.f), 127.f);
      o[j] = f2bf(qv);                        // exact: |int| <= 128
    }
    ushort4 q0; q0.x = o[0]; q0.y = o[1]; q0.z = o[2]; q0.w = o[3];
    ushort4 q1; q1.x = o[4]; q1.y = o[5]; q1.z = o[6]; q1.w = o[7];
    *(ushort4*)(outs[p] + (size_t)row * DIM + tid * 4) = q0;
    *(ushort4*)(outs[p] + (size_t)row * DIM + 1024 + tid * 4) = q1;
  }
}

// ---------------- single-tensor LN (for the o projection) ----------------
template<int MODE>
__global__ __launch_bounds__(256) void ln_kernel(
    const float* __restrict__ x, const float* __restrict__ g, const float* __restrict__ bias,
    unsigned* __restrict__ ambits, unsigned short* __restrict__ xq)
{
  const int row = blockIdx.x, tid = threadIdx.x;
  const float* xr = x + (size_t)row * DIM;
  float4 a0 = *(const float4*)(xr + tid * 4);
  float4 a1 = *(const float4*)(xr + 1024 + tid * 4);
  float s  = a0.x + a0.y + a0.z + a0.w + a1.x + a1.y + a1.z + a1.w;
  float sq = a0.x*a0.x + a0.y*a0.y + a0.z*a0.z + a0.w*a0.w
           + a1.x*a1.x + a1.y*a1.y + a1.z*a1.z + a1.w*a1.w;
  __shared__ float red[256];
  float ts = blockReduceSum(s, red);
  float tqq = blockReduceSum(sq, red);
  float mu = ts * (1.f / DIM);
  float var = tqq * (1.f / DIM) - mu * mu;
  float rstd = 1.f / sqrtf(var + 1e-5f);
  float4 g0 = *(const float4*)(g + tid * 4);
  float4 g1 = *(const float4*)(g + 1024 + tid * 4);
  float4 b0 = *(const float4*)(bias + tid * 4);
  float4 b1 = *(const float4*)(bias + 1024 + tid * 4);
  float y[8];
  y[0] = (a0.x - mu) * rstd * g0.x + b0.x;
  y[1] = (a0.y - mu) * rstd * g0.y + b0.y;
  y[2] = (a0.z - mu) * rstd * g0.z + b0.z;
  y[3] = (a0.w - mu) * rstd * g0.w + b0.w;
  y[4] = (a1.x - mu) * rstd * g1.x + b1.x;
  y[5] = (a1.y - mu) * rstd * g1.y + b1.y;
  y[6] = (a1.z - mu) * rstd * g1.z + b1.z;
  y[7] = (a1.w - mu) * rstd * g1.w + b1.w;
  if (MODE == 0) {
    float m = 0.f;
    #pragma unroll
    for (int j = 0; j < 8; ++j) m = fmaxf(m, fabsf(y[j]));
    float bm = blockReduceMax(m, red);
    if (tid == 0) atomicMax(ambits, __float_as_uint(bm));
  } else {
    float sc = 127.f / fmaxf(__uint_as_float(*ambits), 1e-5f);
    unsigned short o[8];
    #pragma unroll
    for (int j = 0; j < 8; ++j) {
      float qv = rintf(y[j] * sc);
      qv = fminf(fmaxf(qv, -128.f), 127.f);
      o[j] = f2bf(qv);
    }
    ushort4 q0; q0.x = o[0]; q0.y = o[1]; q0.z = o[2]; q0.w = o[3];
    ushort4 q1; q1.x = o[4]; q1.y = o[5]; q1.z = o[6]; q1.w = o[7];
    *(ushort4*)(xq + (size_t)row * DIM + tid * 4) = q0;
    *(ushort4*)(xq + (size_t)row * DIM + 1024 + tid * 4) = q1;
  }
}

// ---------------- quantized GEMM, m97 structure: global_load_lds staging ----------------
// OMODE: 0 = fp32 out, 1 = fp16 out
template<int OMODE>
__global__ __launch_bounds__(256) void gemm_bt(
    const unsigned short* __restrict__ A, const unsigned short* __restrict__ Bt,
    void* __restrict__ Cp0, const float* __restrict__ stats, int wi)
{
  const int tid = threadIdx.x;
  const int lane = tid & 63;
  const int w = tid >> 6;
  const int wm = w >> 1, wn = w & 1;
  const int quad = lane >> 4, l16 = lane & 15;
  const int bm = blockIdx.x * 128, bn = blockIdx.y * 128;

  // unpadded, contiguous row-major [128][64] — required by global_load_lds lane scatter
  __shared__ __align__(16) unsigned short As[128 * 64];
  __shared__ __align__(16) unsigned short Bs[128 * 64];

  // per-chunk geometry: chunk c (1 KiB) = rows c*8..c*8+8; lane i -> row c*8+(i>>3), col (i&7)*8
  const int srow_off = lane >> 3;        // 0..7
  const int scol     = (lane & 7) * 8;   // halves

  floatx4 acc[4][4];
  #pragma unroll
  for (int i = 0; i < 4; ++i)
    #pragma unroll
    for (int j = 0; j < 4; ++j) acc[i][j] = {0.f, 0.f, 0.f, 0.f};

  for (int k0 = 0; k0 < DIM; k0 += 64) {
    #pragma unroll
    for (int i = 0; i < 4; ++i) {
      int c = i * 4 + w;                 // wave-uniform chunk id
      int row = c * 8 + srow_off;
      gload_lds16(A  + (size_t)(bm + row) * DIM + k0 + scol, &As[c * 512]);
      gload_lds16(Bt + (size_t)(bn + row) * DIM + k0 + scol, &Bs[c * 512]);
    }
    __syncthreads();
    #pragma unroll
    for (int kc = 0; kc < 2; ++kc) {
      short8 af[4], bf[4];
      #pragma unroll
      for (int i = 0; i < 4; ++i)
        af[i] = *(const short8*)&As[(wm * 64 + i * 16 + l16) * 64 + kc * 32 + quad * 8];
      #pragma unroll
      for (int j = 0; j < 4; ++j)
        bf[j] = *(const short8*)&Bs[(wn * 64 + j * 16 + l16) * 64 + kc * 32 + quad * 8];
      #pragma unroll
      for (int i = 0; i < 4; ++i)
        #pragma unroll
        for (int j = 0; j < 4; ++j)
          acc[i][j] = __builtin_amdgcn_mfma_f32_16x16x32_bf16(af[i], bf[j], acc[i][j], 0, 0, 0);
    }
    __syncthreads();
  }

  const unsigned* am = (const unsigned*)(stats + 8);
  float scale = stats[4 + wi] * fmaxf(__uint_as_float(am[wi]), 1e-5f) * (1.f / 127.f);
  #pragma unroll
  for (int i = 0; i < 4; ++i)
    #pragma unroll
    for (int j = 0; j < 4; ++j)
      #pragma unroll
      for (int r = 0; r < 4; ++r) {
        int m = bm + wm * 64 + i * 16 + quad * 4 + r;
        int n = bn + wn * 64 + j * 16 + l16;
        size_t idx = (size_t)m * DIM + n;
        float v = acc[i][j][r] * scale;
        if (OMODE == 0) ((float*)Cp0)[idx] = v;
        else            ((unsigned short*)Cp0)[idx] = f2h(v);
      }
}

// ---------------- rope (fp16; angle = head_index * inv; q gets (1/sqrt(128))*log2e folded) ----------------
__global__ __launch_bounds__(256) void rope_kernel(unsigned short* q, unsigned short* k)
{
  const float SC = 0.12751741769011063f;   // (1/sqrt(128)) * log2(e)
  int idx = blockIdx.x * 256 + threadIdx.x;
  int p = idx & 63;
  int h = (idx >> 6) & (HEADS - 1);
  int r = idx >> 10;
  float inv = exp2f((float)p * -0.20762050593046f);  // 10000^(-p/64)
  float ang = (float)h * inv;
  float sn, cs;
  __sincosf(ang, &sn, &cs);
  size_t base = (size_t)r * DIM + h * HDIM + 2 * p;
  {
    float a = h2f(q[base]), b = h2f(q[base + 1]);
    q[base]     = f2h((a * cs - b * sn) * SC);
    q[base + 1] = f2h((a * sn + b * cs) * SC);
  }
  {
    float a = h2f(k[base]), b = h2f(k[base + 1]);
    k[base]     = f2h(a * cs - b * sn);
    k[base + 1] = f2h(a * sn + b * cs);
  }
}

// ---------------- transpose V: [b*S+s][h*128+d] -> [(b*16+h)*128+d][s] ----------------
__global__ __launch_bounds__(256) void transpose_v(
    const unsigned short* __restrict__ vin, unsigned short* __restrict__ vout)
{
  __shared__ __align__(16) unsigned short t[64][72];
  const int tid = threadIdx.x;
  const int c0 = blockIdx.x * 64, r0 = blockIdx.y * 64;
  #pragma unroll
  for (int c = 0; c < 2; ++c) {
    int idx = c * 256 + tid;
    int row = idx >> 3, cb = (idx & 7) << 3;
    *(uint4*)&t[row][cb] = *(const uint4*)(vin + (size_t)(r0 + row) * DIM + c0 + cb);
  }
  __syncthreads();
  const int b = r0 >> 11, s0 = r0 & (SEQ - 1);
  const int h = c0 >> 7, d0 = c0 & (HDIM - 1);
  #pragma unroll
  for (int c = 0; c < 2; ++c) {
    int idx = c * 256 + tid;
    int drow = idx >> 3, sb = (idx & 7) << 3;
    union { unsigned short u[8]; uint4 v; } pk;
    #pragma unroll
    for (int j = 0; j < 8; ++j) pk.u[j] = t[sb + j][drow];
    *(uint4*)(vout + (size_t)((b * HEADS + h) * HDIM + d0 + drow) * SEQ + s0 + sb) = pk.v;
  }
}

// ---------------- flash attention: S^T form, 2 Q-fragments/wave, reg-prefetch K/V ----------------
// Q pre-scaled by (1/sqrt(128))*log2(e); softmax in exp2 domain.
__global__ __launch_bounds__(256, 2) void flash_attn(
    const unsigned short* __restrict__ qf, const unsigned short* __restrict__ kf,
    const unsigned short* __restrict__ vt, float* __restrict__ o)
{
  const int tid = threadIdx.x;
  const int lane = tid & 63;
  const int w = tid >> 6;
  const int quad = lane >> 4;
  const int l16 = lane & 15;
  const int qt = blockIdx.x;
  const int bh = blockIdx.y;
  const int b = bh >> 4;
  const int h = bh & 15;

  __shared__ __align__(16) unsigned short Ks[64][136];
  __shared__ __align__(16) unsigned short Vs[128][72];      // V^T tile: [d][t]
  __shared__ __align__(16) unsigned short Ps[4][32][72];    // per-wave P: [q 0..31][t 0..63]

  // Q fragments (B-operand): wave owns 32 q-rows, two 16-row fragments
  const size_t qbase = ((size_t)(b * SEQ + qt * 128 + w * 32 + l16)) * DIM + h * HDIM;
  short8 qa[2][4];
  #pragma unroll
  for (int f = 0; f < 2; ++f)
    #pragma unroll
    for (int kc = 0; kc < 4; ++kc)
      qa[f][kc] = *(const short8*)(qf + qbase + (size_t)f * 16 * DIM + kc * 32 + quad * 8);

  float m_q[2] = {-INFINITY, -INFINITY};
  float l_q[2] = {0.f, 0.f};
  floatx4 accO0[8], accO1[8];           // O^T: rows d=dt*16+quad*4+r, col q = f*16+l16
  #pragma unroll
  for (int i = 0; i < 8; ++i) { accO0[i] = {0.f, 0.f, 0.f, 0.f}; accO1[i] = {0.f, 0.f, 0.f, 0.f}; }

  const unsigned short* kg = kf + (size_t)(b * SEQ) * DIM + h * HDIM;
  const unsigned short* vg = vt + (size_t)bh * HDIM * SEQ;

  // register prefetch buffers (one K/V tile per block iteration)
  uint4 kreg[4], vreg[4];
  #pragma unroll
  for (int i = 0; i < 4; ++i) {
    int idx = i * 256 + tid;
    kreg[i] = *(const uint4*)(kg + (size_t)(idx >> 4) * DIM + (idx & 15) * 8);
    vreg[i] = *(const uint4*)(vg + (size_t)(idx >> 3) * SEQ + (idx & 7) * 8);
  }

  for (int kt = 0; kt < SEQ / 64; ++kt) {
    __syncthreads();                    // prior tile's LDS reads complete
    #pragma unroll
    for (int i = 0; i < 4; ++i) {
      int idx = i * 256 + tid;
      *(uint4*)&Ks[idx >> 4][(idx & 15) * 8] = kreg[i];
      *(uint4*)&Vs[idx >> 3][(idx & 7) * 8]  = vreg[i];
    }
    __syncthreads();
    if (kt + 1 < SEQ / 64) {            // issue next tile's loads; latency hidden by compute
      #pragma unroll
      for (int i = 0; i < 4; ++i) {
        int idx = i * 256 + tid;
        kreg[i] = *(const uint4*)(kg + (size_t)((kt + 1) * 64 + (idx >> 4)) * DIM + (idx & 15) * 8);
        vreg[i] = *(const uint4*)(vg + (size_t)(idx >> 3) * SEQ + (kt + 1) * 64 + (idx & 7) * 8);
      }
    }

    // S^T = K Q'^T : lane q = f*16+l16, keys t = jt*16 + quad*4 + r
    float sreg[2][4][4];
    #pragma unroll
    for (int jt = 0; jt < 4; ++jt) {
      floatx4 a0 = {0.f, 0.f, 0.f, 0.f}, a1 = {0.f, 0.f, 0.f, 0.f};
      #pragma unroll
      for (int kc = 0; kc < 4; ++kc) {
        short8 kb = *(const short8*)&Ks[jt * 16 + l16][kc * 32 + quad * 8];
        a0 = __builtin_amdgcn_mfma_f32_16x16x32_f16(
            __builtin_bit_cast(half8, kb), __builtin_bit_cast(half8, qa[0][kc]), a0, 0, 0, 0);
        a1 = __builtin_amdgcn_mfma_f32_16x16x32_f16(
            __builtin_bit_cast(half8, kb), __builtin_bit_cast(half8, qa[1][kc]), a1, 0, 0, 0);
      }
      #pragma unroll
      for (int r = 0; r < 4; ++r) { sreg[0][jt][r] = a0[r]; sreg[1][jt][r] = a1[r]; }
    }

    // per-lane online softmax (exp2 domain), one state per fragment
    float alpha[2];
    #pragma unroll
    for (int f = 0; f < 2; ++f) {
      float mx = sreg[f][0][0];
      #pragma unroll
      for (int jt = 0; jt < 4; ++jt)
        #pragma unroll
        for (int r = 0; r < 4; ++r) mx = fmaxf(mx, sreg[f][jt][r]);
      mx = fmaxf(mx, __shfl_xor(mx, 16));
      mx = fmaxf(mx, __shfl_xor(mx, 32));
      float mnew = fmaxf(m_q[f], mx);
      alpha[f] = exp2f(m_q[f] - mnew);
      m_q[f] = mnew;
      float ssum = 0.f;
      #pragma unroll
      for (int jt = 0; jt < 4; ++jt) {
        ushort4 pk;
        float p0 = exp2f(sreg[f][jt][0] - mnew);
        float p1 = exp2f(sreg[f][jt][1] - mnew);
        float p2 = exp2f(sreg[f][jt][2] - mnew);
        float p3 = exp2f(sreg[f][jt][3] - mnew);
        pk.x = f2h(p0); pk.y = f2h(p1); pk.z = f2h(p2); pk.w = f2h(p3);
        ssum += (p0 + p1) + (p2 + p3);
        *(ushort4*)&Ps[w][f * 16 + l16][jt * 16 + quad * 4] = pk;
      }
      ssum += __shfl_xor(ssum, 16);
      ssum += __shfl_xor(ssum, 32);
      l_q[f] = l_q[f] * alpha[f] + ssum;
    }
    #pragma unroll
    for (int dt = 0; dt < 8; ++dt)
      #pragma unroll
      for (int r = 0; r < 4; ++r) { accO0[dt][r] *= alpha[0]; accO1[dt][r] *= alpha[1]; }

    // O^T = O^T + V^T P^T : vf read once, used by both fragments
    #pragma unroll
    for (int kc = 0; kc < 2; ++kc) {
      short8 pf0 = *(const short8*)&Ps[w][l16][kc * 32 + quad * 8];
      short8 pf1 = *(const short8*)&Ps[w][16 + l16][kc * 32 + quad * 8];
      #pragma unroll
      for (int dt = 0; dt < 8; ++dt) {
        short8 vf = *(const short8*)&Vs[dt * 16 + l16][kc * 32 + quad * 8];
        accO0[dt] = __builtin_amdgcn_mfma_f32_16x16x32_f16(
            __builtin_bit_cast(half8, vf), __builtin_bit_cast(half8, pf0), accO0[dt], 0, 0, 0);
        accO1[dt] = __builtin_amdgcn_mfma_f32_16x16x32_f16(
            __builtin_bit_cast(half8, vf), __builtin_bit_cast(half8, pf1), accO1[dt], 0, 0, 0);
      }
    }
  }

  // epilogue: float4 stores, 16B per lane
  #pragma unroll
  for (int f = 0; f < 2; ++f) {
    float invl = 1.0f / l_q[f];
    const size_t obase = (size_t)(b * SEQ + qt * 128 + w * 32 + f * 16 + l16) * DIM + h * HDIM;
    #pragma unroll
    for (int dt = 0; dt < 8; ++dt) {
      floatx4 acc = f == 0 ? accO0[dt] : accO1[dt];
      float4 ov;
      ov.x = acc[0] * invl; ov.y = acc[1] * invl;
      ov.z = acc[2] * invl; ov.w = acc[3] * invl;
      *(float4*)(o + obase + dt * 16 + quad * 4) = ov;
    }
  }
}

// ---------------- host ----------------
extern "C" void kernel_launch(void* const* d_in, const int* in_sizes, int n_in,
                              void* d_out, int out_size, void* d_ws, size_t ws_size,
                              hipStream_t stream)
{
  (void)in_sizes; (void)n_in; (void)out_size; (void)ws_size;
  const float* x = (const float*)d_in[0];
  const float* w[4]; const float* g[4]; const float* bb[4];
  for (int i = 0; i < 4; ++i) {
    w[i]  = (const float*)d_in[1 + 3 * i];
    g[i]  = (const float*)d_in[2 + 3 * i];
    bb[i] = (const float*)d_in[3 + 3 * i];
  }

  char* base = (char*)d_ws;
  size_t off = 0;
  auto alloc = [&](size_t bytes) {
    char* p = base + off;
    off += (bytes + 255) & ~(size_t)255;
    return p;
  };
  const size_t ACT = (size_t)NROWS * DIM * 2;   // one 16-bit activation buffer (16 MB)
  float* stats          = (float*)alloc(64);
  float* part1          = (float*)alloc(4 * 1024 * sizeof(float));
  float* part2          = (float*)alloc(4 * 1024 * 2 * sizeof(float));
  unsigned short* tern  = (unsigned short*)alloc((size_t)4 * WN * 2);
  unsigned short* xq0   = (unsigned short*)alloc(ACT);
  unsigned short* xq1   = (unsigned short*)alloc(ACT);
  unsigned short* xq2   = (unsigned short*)alloc(ACT);
  unsigned short* qh    = (unsigned short*)alloc(ACT);
  unsigned short* kh    = (unsigned short*)alloc(ACT);
  unsigned short* vb    = (unsigned short*)alloc(ACT);
  unsigned short* vtb   = (unsigned short*)alloc(ACT);
  float* oat = (float*)xq0;            // 32 MB overlay: xq0+xq1 dead after the q/k GEMMs
  unsigned short* xqo = xq2;           // dead after the v GEMM
  unsigned* ambits = (unsigned*)(stats + 8);

  hipMemsetAsync(stats, 0, 64, stream);

  dim3 b256(256);
  w_abs_partial<<<dim3(1024, 4), b256, 0, stream>>>(w[0], w[1], w[2], w[3], part1);
  w_delta_final<<<4, b256, 0, stream>>>(part1, stats);
  w_maskquant<<<dim3(1024, 4), b256, 0, stream>>>(w[0], w[1], w[2], w[3], stats, part2, tern);
  w_alpha_final<<<4, b256, 0, stream>>>(part2, stats);

  ln_absmax3<<<NROWS, b256, 0, stream>>>(x, g[0], bb[0], g[1], bb[1], g[2], bb[2], ambits);
  ln_quant3<<<NROWS, b256, 0, stream>>>(x, g[0], bb[0], g[1], bb[1], g[2], bb[2], ambits,
                                        xq0, xq1, xq2);

  dim3 ggrid(NROWS / 128, DIM / 128);
  gemm_bt<1><<<ggrid, b256, 0, stream>>>(xq0, tern + (size_t)0 * WN, qh, stats, 0);
  gemm_bt<1><<<ggrid, b256, 0, stream>>>(xq1, tern + (size_t)1 * WN, kh, stats, 1);
  gemm_bt<1><<<ggrid, b256, 0, stream>>>(xq2, tern + (size_t)2 * WN, vb, stats, 2);

  rope_kernel<<<NROWS * 1024 / 256, b256, 0, stream>>>(qh, kh);
  transpose_v<<<dim3(DIM / 64, NROWS / 64), b256, 0, stream>>>(vb, vtb);
  flash_attn<<<dim3(SEQ / 128, 32), b256, 0, stream>>>(qh, kh, vtb, oat);

  ln_kernel<0><<<NROWS, b256, 0, stream>>>(oat, g[3], bb[3], ambits + 3, nullptr);
  ln_kernel<1><<<NROWS, b256, 0, stream>>>(oat, g[3], bb[3], ambits + 3, xqo);
  gemm_bt<0><<<ggrid, b256, 0, stream>>>(xqo, tern + (size_t)3 * WN, (float*)d_out, stats, 3);
}